// Round 2
// baseline (571.622 us; speedup 1.0000x reference)
//
#include <hip/hip_runtime.h>
#include <hip/hip_bf16.h>
#include <stdint.h>

#define T_TOK 1024
#define HDIM 2048
#define DDIM 2048
#define NE 8

typedef unsigned int uint;
typedef unsigned short ushort;

typedef __bf16 bf16x8 __attribute__((ext_vector_type(8)));
typedef float f32x4 __attribute__((ext_vector_type(4)));

typedef __attribute__((address_space(1))) const void v_g;
typedef __attribute__((address_space(3))) void v_l;

__device__ __forceinline__ ushort f2bf(float f) {
  uint u = __float_as_uint(f);
  u += 0x7fffu + ((u >> 16) & 1u);
  return (ushort)(u >> 16);
}
__device__ __forceinline__ float bf2f(ushort b) {
  uint u = (uint)b << 16;
  return __uint_as_float(u);
}

// e2m1 nibble * 2^(sc-127) -> bf16 bits (exact; flush exp<=0 to signed zero)
__device__ __forceinline__ uint dq1(uint nib, int sc) {
  uint m = nib & 7u;
  int e = (int)(m >> 1);
  int be = sc + e - 1;                 // m>=2: sc+e-1 ; m==1: sc-1 (0.5*2^(sc-127))
  uint mant = (e != 0) ? ((m & 1u) << 6) : 0u;
  uint r = ((m != 0u) && (be > 0)) ? (((uint)be << 7) | mant) : 0u;
  return r | ((nib & 8u) << 12);
}
__device__ __forceinline__ uint dq2(uint b, int sc) {
  return dq1(b & 15u, sc) | (dq1((b >> 4) & 15u, sc) << 16);
}

// ---------------- RMSNorm + router (f32 logits, top-4 softmax) ----------------
__global__ __launch_bounds__(256) void router_kernel(
    const float* __restrict__ x, const float* __restrict__ nw,
    const float* __restrict__ rw, const float* __restrict__ rb,
    ushort* __restrict__ thi, ushort* __restrict__ tlo, float* __restrict__ scores)
{
  const int t = blockIdx.x, tid = threadIdx.x;
  const float4* xr = (const float4*)(x + (size_t)t * HDIM);
  float4 v0 = xr[tid * 2], v1 = xr[tid * 2 + 1];
  float ss = v0.x*v0.x + v0.y*v0.y + v0.z*v0.z + v0.w*v0.w
           + v1.x*v1.x + v1.y*v1.y + v1.z*v1.z + v1.w*v1.w;
  __shared__ float red[256];
  red[tid] = ss;
  __syncthreads();
  for (int s = 128; s > 0; s >>= 1) {
    if (tid < s) red[tid] += red[tid + s];
    __syncthreads();
  }
  const float rstd = rsqrtf(red[0] * (1.0f / HDIM) + 1e-5f);
  float xv[8] = {v0.x, v0.y, v0.z, v0.w, v1.x, v1.y, v1.z, v1.w};
  float lp[NE];
#pragma unroll
  for (int e = 0; e < NE; ++e) lp[e] = 0.f;
  union { ushort us[8]; uint4 v; } pkh, pkl;
  const int h0 = tid * 8;
#pragma unroll
  for (int j = 0; j < 8; ++j) {
    int h = h0 + j;
    float tn = xv[j] * rstd * nw[h];
    ushort hb = f2bf(tn);
    pkh.us[j] = hb;
    pkl.us[j] = f2bf(tn - bf2f(hb));
#pragma unroll
    for (int e = 0; e < NE; ++e) lp[e] += tn * rw[h * NE + e];
  }
  *(uint4*)(thi + (size_t)t * HDIM + h0) = pkh.v;
  *(uint4*)(tlo + (size_t)t * HDIM + h0) = pkl.v;
#pragma unroll
  for (int e = 0; e < NE; ++e)
#pragma unroll
    for (int off = 32; off > 0; off >>= 1) lp[e] += __shfl_down(lp[e], off);
  __shared__ float wred[4][NE];
  if ((tid & 63) == 0) {
#pragma unroll
    for (int e = 0; e < NE; ++e) wred[tid >> 6][e] = lp[e];
  }
  __syncthreads();
  if (tid == 0) {
    float lg[NE];
#pragma unroll
    for (int e = 0; e < NE; ++e)
      lg[e] = wred[0][e] + wred[1][e] + wred[2][e] + wred[3][e] + rb[e];
    bool used[NE] = {false, false, false, false, false, false, false, false};
    float tv[4]; int ti[4];
    for (int s = 0; s < 4; ++s) {          // ties: lowest index first (strict >)
      float best = -3.4e38f; int bi = 0;
      for (int e = 0; e < NE; ++e)
        if (!used[e] && lg[e] > best) { best = lg[e]; bi = e; }
      used[bi] = true; tv[s] = best; ti[s] = bi;
    }
    float den = 0.f, ev[4];
    for (int s = 0; s < 4; ++s) { ev[s] = expf(tv[s] - tv[0]); den += ev[s]; }
    float so[NE] = {0, 0, 0, 0, 0, 0, 0, 0};
    for (int s = 0; s < 4; ++s) so[ti[s]] = ev[s] / den;
#pragma unroll
    for (int e = 0; e < NE; ++e) scores[t * NE + e] = so[e];
  }
}

// ---------------- mxfp4 -> bf16 pre-dequant (memory-bound) ----------------
__global__ __launch_bounds__(256) void dequant_kernel(
    const int* __restrict__ gub, const int* __restrict__ gus,
    const int* __restrict__ dnb, const int* __restrict__ dns,
    ushort* __restrict__ wgu, ushort* __restrict__ wdn)
{
  const int NG = NE * 4096 * 64;
  const int ND = NE * 2048 * 64;
  int tidg = blockIdx.x * 256 + threadIdx.x;
  if (tidg >= NG + ND) return;
  const int* qb; const int* qs; ushort* dst; int bi;
  if (tidg < NG) { bi = tidg; qb = gub; qs = gus; dst = wgu; }
  else           { bi = tidg - NG; qb = dnb; qs = dns; dst = wdn; }
  int sc = qs[bi];
  const int4* bp = (const int4*)(qb + (size_t)bi * 16);
  int4 q0 = bp[0], q1 = bp[1], q2 = bp[2], q3 = bp[3];
  uint w[16];
  w[0]=dq2(q0.x,sc);  w[1]=dq2(q0.y,sc);  w[2]=dq2(q0.z,sc);  w[3]=dq2(q0.w,sc);
  w[4]=dq2(q1.x,sc);  w[5]=dq2(q1.y,sc);  w[6]=dq2(q1.z,sc);  w[7]=dq2(q1.w,sc);
  w[8]=dq2(q2.x,sc);  w[9]=dq2(q2.y,sc);  w[10]=dq2(q2.z,sc); w[11]=dq2(q2.w,sc);
  w[12]=dq2(q3.x,sc); w[13]=dq2(q3.y,sc); w[14]=dq2(q3.z,sc); w[15]=dq2(q3.w,sc);
  uint4* o = (uint4*)(dst + (size_t)bi * 32);
  o[0] = make_uint4(w[0], w[1], w[2], w[3]);
  o[1] = make_uint4(w[4], w[5], w[6], w[7]);
  o[2] = make_uint4(w[8], w[9], w[10], w[11]);
  o[3] = make_uint4(w[12], w[13], w[14], w[15]);
}

// -------- tiled bf16 GEMM, split-precision A (hi+lo), C = A * B^T ----------
// 128x128 tile, BK=64. MODE 0: gate_up + bias + GLU + score-scale -> mid (hi/lo)
// MODE 1: down: atomicAdd(out, acc + s*bias) for s != 0
template<int MODE, bool PREDEQ>
__global__ __launch_bounds__(256) void mx_gemm(
    const ushort* __restrict__ Ahi_base,
    const ushort* __restrict__ Alo_base,
    const ushort* __restrict__ Bw,
    const int* __restrict__ qblocks,
    const int* __restrict__ qscales,
    const float* __restrict__ bias,
    const float* __restrict__ scores,
    ushort* __restrict__ midH,
    ushort* __restrict__ midL,
    float* __restrict__ outp)
{
  constexpr int NTOT = (MODE == 0) ? 2 * DDIM : HDIM;
  constexpr int K    = (MODE == 0) ? HDIM : DDIM;
  const int nt = blockIdx.x, mt = blockIdx.y, e = blockIdx.z;
  const int m0 = mt * 128, n0 = nt * 128;
  const size_t aoff = (MODE == 0) ? (size_t)0 : (size_t)e * T_TOK * DDIM;
  const ushort* AH = Ahi_base + aoff;
  const ushort* AL = Alo_base + aoff;

  __shared__ __align__(16) ushort AsH[128 * 64];
  __shared__ __align__(16) ushort AsL[128 * 64];
  __shared__ __align__(16) ushort Bs[128 * 64];

  const int tid = threadIdx.x;
  const int lane = tid & 63;
  const int wv = tid >> 6;
  const int wm = wv >> 1, wn = wv & 1;
  const int fr = lane & 15, kg = lane >> 4;

  f32x4 acc[4][4];
#pragma unroll
  for (int i = 0; i < 4; ++i)
#pragma unroll
    for (int j = 0; j < 4; ++j) acc[i][j] = f32x4{0.f, 0.f, 0.f, 0.f};

  for (int kt = 0; kt < K / 64; ++kt) {
    // stage A hi/lo: global_load_lds, source pre-swizzled (chunk' = chunk ^ (row&7))
#pragma unroll
    for (int j = 0; j < 4; ++j) {
      int cidx = tid + 256 * j;
      int row = cidx >> 3, ck = cidx & 7;
      int sck = ck ^ (row & 7);
      size_t go = (size_t)(m0 + row) * K + kt * 64 + sck * 8;
      __builtin_amdgcn_global_load_lds((v_g*)(AH + go), (v_l*)((char*)AsH + cidx * 16), 16, 0, 0);
      __builtin_amdgcn_global_load_lds((v_g*)(AL + go), (v_l*)((char*)AsL + cidx * 16), 16, 0, 0);
    }
    if constexpr (PREDEQ) {
#pragma unroll
      for (int j = 0; j < 4; ++j) {
        int cidx = tid + 256 * j;
        int row = cidx >> 3, ck = cidx & 7;
        int sck = ck ^ (row & 7);
        const ushort* g = Bw + ((size_t)e * NTOT + n0 + row) * K + kt * 64 + sck * 8;
        __builtin_amdgcn_global_load_lds((v_g*)g, (v_l*)((char*)Bs + cidx * 16), 16, 0, 0);
      }
    } else {
      const int brow = tid >> 1, bblk = tid & 1;
      int kb = kt * 2 + bblk;
      size_t bi = ((size_t)e * NTOT + n0 + brow) * (K / 32) + kb;
      int sc = qscales[bi];
      const int4* bp = (const int4*)(qblocks + bi * 16);
      int4 q0 = bp[0], q1 = bp[1], q2 = bp[2], q3 = bp[3];
      uint w[16];
      w[0]=dq2(q0.x,sc);  w[1]=dq2(q0.y,sc);  w[2]=dq2(q0.z,sc);  w[3]=dq2(q0.w,sc);
      w[4]=dq2(q1.x,sc);  w[5]=dq2(q1.y,sc);  w[6]=dq2(q1.z,sc);  w[7]=dq2(q1.w,sc);
      w[8]=dq2(q2.x,sc);  w[9]=dq2(q2.y,sc);  w[10]=dq2(q2.z,sc); w[11]=dq2(q2.w,sc);
      w[12]=dq2(q3.x,sc); w[13]=dq2(q3.y,sc); w[14]=dq2(q3.z,sc); w[15]=dq2(q3.w,sc);
#pragma unroll
      for (int q = 0; q < 4; ++q) {
        int ck = bblk * 4 + q;
        int sk = ck ^ (brow & 7);
        *(uint4*)((char*)Bs + brow * 128 + sk * 16) =
            make_uint4(w[4*q], w[4*q+1], w[4*q+2], w[4*q+3]);
      }
    }
    __syncthreads();
#pragma unroll
    for (int kh = 0; kh < 2; ++kh) {
      bf16x8 aH[4], aL[4], bF[4];
#pragma unroll
      for (int mi = 0; mi < 4; ++mi) {
        int r = wm * 64 + mi * 16 + fr;
        int ck = (kh * 4 + kg) ^ (r & 7);
        aH[mi] = *(const bf16x8*)((const char*)AsH + r * 128 + ck * 16);
        aL[mi] = *(const bf16x8*)((const char*)AsL + r * 128 + ck * 16);
      }
#pragma unroll
      for (int ni = 0; ni < 4; ++ni) {
        int r = wn * 64 + ni * 16 + fr;
        int ck = (kh * 4 + kg) ^ (r & 7);
        bF[ni] = *(const bf16x8*)((const char*)Bs + r * 128 + ck * 16);
      }
#pragma unroll
      for (int mi = 0; mi < 4; ++mi)
#pragma unroll
        for (int ni = 0; ni < 4; ++ni) {
          acc[mi][ni] = __builtin_amdgcn_mfma_f32_16x16x32_bf16(aH[mi], bF[ni], acc[mi][ni], 0, 0, 0);
          acc[mi][ni] = __builtin_amdgcn_mfma_f32_16x16x32_bf16(aL[mi], bF[ni], acc[mi][ni], 0, 0, 0);
        }
    }
    __syncthreads();
  }

  const int c = lane & 15, rg = lane >> 4;
  const int tbase = m0 + wm * 64, nbase = n0 + wn * 64;
  if constexpr (MODE == 0) {
#pragma unroll
    for (int mi = 0; mi < 4; ++mi)
#pragma unroll
      for (int ni = 0; ni < 4; ++ni) {
        int n = nbase + ni * 16 + c;
        float bv = bias[(size_t)e * NTOT + n];
#pragma unroll
        for (int r = 0; r < 4; ++r) {
          int t = tbase + mi * 16 + rg * 4 + r;
          float val = acc[mi][ni][r] + bv;
          float other = __shfl_xor(val, 1);
          if (!(c & 1)) {
            float g = fminf(val, 7.0f);
            float u = fminf(fmaxf(other, -7.0f), 7.0f);
            float glu = g / (1.0f + expf(-1.702f * g));
            float mv = (u + 1.0f) * glu;
            float s = scores[t * NE + e];
            float m = mv * s;
            ushort hb = f2bf(m);
            size_t idx = ((size_t)e * T_TOK + t) * DDIM + ((uint)n >> 1);
            midH[idx] = hb;
            midL[idx] = f2bf(m - bf2f(hb));
          }
        }
      }
  } else {
#pragma unroll
    for (int mi = 0; mi < 4; ++mi)
#pragma unroll
      for (int ni = 0; ni < 4; ++ni) {
        int n = nbase + ni * 16 + c;
        float dbv = bias[(size_t)e * NTOT + n];
#pragma unroll
        for (int r = 0; r < 4; ++r) {
          int t = tbase + mi * 16 + rg * 4 + r;
          float s = scores[t * NE + e];
          if (s != 0.f) atomicAdd(outp + (size_t)t * HDIM + n, acc[mi][ni][r] + s * dbv);
        }
      }
  }
}

extern "C" void kernel_launch(void* const* d_in, const int* in_sizes, int n_in,
                              void* d_out, int out_size, void* d_ws, size_t ws_size,
                              hipStream_t stream)
{
  const float* x      = (const float*)d_in[0];
  const float* nw     = (const float*)d_in[1];
  const float* rw     = (const float*)d_in[2];
  const float* rb     = (const float*)d_in[3];
  const int*   gus    = (const int*)d_in[4];
  const int*   gub    = (const int*)d_in[5];
  const float* gubias = (const float*)d_in[6];
  const int*   dns    = (const int*)d_in[7];
  const int*   dnb    = (const int*)d_in[8];
  const float* dnbias = (const float*)d_in[9];

  char* ws = (char*)d_ws;
  const size_t SZ_WGU = (size_t)NE * 4096 * 2048 * 2;   // 134 MB
  const size_t SZ_WDN = (size_t)NE * 2048 * 2048 * 2;   //  67 MB
  const size_t SZ_T   = (size_t)T_TOK * HDIM * 2;       //   4 MB (per plane)
  const size_t SZ_MID = (size_t)NE * T_TOK * DDIM * 2;  //  33.5 MB (per plane)
  const size_t SZ_SC  = (size_t)T_TOK * NE * 4;

  const size_t need_act = 2 * SZ_T + 2 * SZ_MID + SZ_SC;
  const bool predeq = ws_size >= SZ_WGU + SZ_WDN + need_act;
  ushort* wgu = (ushort*)ws;
  ushort* wdn = (ushort*)(ws + SZ_WGU);
  char* base2 = predeq ? (ws + SZ_WGU + SZ_WDN) : ws;
  ushort* thi    = (ushort*)base2;
  ushort* tlo    = (ushort*)(base2 + SZ_T);
  ushort* midHp  = (ushort*)(base2 + 2 * SZ_T);
  ushort* midLp  = (ushort*)(base2 + 2 * SZ_T + SZ_MID);
  float*  scores = (float*)(base2 + 2 * SZ_T + 2 * SZ_MID);
  float*  outp   = (float*)d_out;

  router_kernel<<<T_TOK, 256, 0, stream>>>(x, nw, rw, rb, thi, tlo, scores);
  hipMemcpyAsync(d_out, (void*)x, (size_t)T_TOK * HDIM * 4, hipMemcpyDeviceToDevice, stream);
  if (predeq) {
    dequant_kernel<<<(NE * 4096 * 64 + NE * 2048 * 64) / 256, 256, 0, stream>>>(
        gub, gus, dnb, dns, wgu, wdn);
    mx_gemm<0, true><<<dim3(32, 8, NE), 256, 0, stream>>>(
        thi, tlo, wgu, nullptr, nullptr, gubias, scores, midHp, midLp, nullptr);
    mx_gemm<1, true><<<dim3(16, 8, NE), 256, 0, stream>>>(
        midHp, midLp, wdn, nullptr, nullptr, dnbias, scores, nullptr, nullptr, outp);
  } else {
    mx_gemm<0, false><<<dim3(32, 8, NE), 256, 0, stream>>>(
        thi, tlo, nullptr, gub, gus, gubias, scores, midHp, midLp, nullptr);
    mx_gemm<1, false><<<dim3(16, 8, NE), 256, 0, stream>>>(
        midHp, midLp, nullptr, dnb, dns, dnbias, scores, nullptr, nullptr, outp);
  }
}

// Round 3
// 477.346 us; speedup vs baseline: 1.1975x; 1.1975x over previous
//
#include <hip/hip_runtime.h>
#include <hip/hip_bf16.h>
#include <stdint.h>

#define T_TOK 1024
#define HDIM 2048
#define DDIM 2048
#define NE 8

typedef unsigned int uint;
typedef unsigned short ushort;

typedef __bf16 bf16x8 __attribute__((ext_vector_type(8)));
typedef float f32x4 __attribute__((ext_vector_type(4)));

typedef __attribute__((address_space(1))) const void v_g;
typedef __attribute__((address_space(3))) void v_l;

__device__ __forceinline__ ushort f2bf(float f) {
  uint u = __float_as_uint(f);
  u += 0x7fffu + ((u >> 16) & 1u);
  return (ushort)(u >> 16);
}
__device__ __forceinline__ float bf2f(ushort b) {
  uint u = (uint)b << 16;
  return __uint_as_float(u);
}

// e2m1 nibble * 2^(sc-127) -> bf16 bits (exact; flush exp<=0 to signed zero)
__device__ __forceinline__ uint dq1(uint nib, int sc) {
  uint m = nib & 7u;
  int e = (int)(m >> 1);
  int be = sc + e - 1;
  uint mant = (e != 0) ? ((m & 1u) << 6) : 0u;
  uint r = ((m != 0u) && (be > 0)) ? (((uint)be << 7) | mant) : 0u;
  return r | ((nib & 8u) << 12);
}
__device__ __forceinline__ uint dq2(uint b, int sc) {
  return dq1(b & 15u, sc) | (dq1((b >> 4) & 15u, sc) << 16);
}

// ---------------- RMSNorm + router (f32 logits, top-4 softmax) ----------------
__global__ __launch_bounds__(256) void router_kernel(
    const float* __restrict__ x, const float* __restrict__ nw,
    const float* __restrict__ rw, const float* __restrict__ rb,
    ushort* __restrict__ thi, ushort* __restrict__ tlo, float* __restrict__ scores)
{
  const int t = blockIdx.x, tid = threadIdx.x;
  const float4* xr = (const float4*)(x + (size_t)t * HDIM);
  float4 v0 = xr[tid * 2], v1 = xr[tid * 2 + 1];
  float ss = v0.x*v0.x + v0.y*v0.y + v0.z*v0.z + v0.w*v0.w
           + v1.x*v1.x + v1.y*v1.y + v1.z*v1.z + v1.w*v1.w;
  __shared__ float red[256];
  red[tid] = ss;
  __syncthreads();
  for (int s = 128; s > 0; s >>= 1) {
    if (tid < s) red[tid] += red[tid + s];
    __syncthreads();
  }
  const float rstd = rsqrtf(red[0] * (1.0f / HDIM) + 1e-5f);
  float xv[8] = {v0.x, v0.y, v0.z, v0.w, v1.x, v1.y, v1.z, v1.w};
  float lp[NE];
#pragma unroll
  for (int e = 0; e < NE; ++e) lp[e] = 0.f;
  union { ushort us[8]; uint4 v; } pkh, pkl;
  const int h0 = tid * 8;
#pragma unroll
  for (int j = 0; j < 8; ++j) {
    int h = h0 + j;
    float tn = xv[j] * rstd * nw[h];
    ushort hb = f2bf(tn);
    pkh.us[j] = hb;
    pkl.us[j] = f2bf(tn - bf2f(hb));
#pragma unroll
    for (int e = 0; e < NE; ++e) lp[e] += tn * rw[h * NE + e];
  }
  *(uint4*)(thi + (size_t)t * HDIM + h0) = pkh.v;
  *(uint4*)(tlo + (size_t)t * HDIM + h0) = pkl.v;
#pragma unroll
  for (int e = 0; e < NE; ++e)
#pragma unroll
    for (int off = 32; off > 0; off >>= 1) lp[e] += __shfl_down(lp[e], off);
  __shared__ float wred[4][NE];
  if ((tid & 63) == 0) {
#pragma unroll
    for (int e = 0; e < NE; ++e) wred[tid >> 6][e] = lp[e];
  }
  __syncthreads();
  if (tid == 0) {
    float lg[NE];
#pragma unroll
    for (int e = 0; e < NE; ++e)
      lg[e] = wred[0][e] + wred[1][e] + wred[2][e] + wred[3][e] + rb[e];
    bool used[NE] = {false, false, false, false, false, false, false, false};
    float tv[4]; int ti[4];
    for (int s = 0; s < 4; ++s) {          // ties: lowest index first (strict >)
      float best = -3.4e38f; int bi = 0;
      for (int e = 0; e < NE; ++e)
        if (!used[e] && lg[e] > best) { best = lg[e]; bi = e; }
      used[bi] = true; tv[s] = best; ti[s] = bi;
    }
    float den = 0.f, ev[4];
    for (int s = 0; s < 4; ++s) { ev[s] = expf(tv[s] - tv[0]); den += ev[s]; }
    float so[NE] = {0, 0, 0, 0, 0, 0, 0, 0};
    for (int s = 0; s < 4; ++s) so[ti[s]] = ev[s] / den;
#pragma unroll
    for (int e = 0; e < NE; ++e) scores[t * NE + e] = so[e];
  }
}

// ------------- per-expert token compaction (deterministic prefix scan) --------
__global__ __launch_bounds__(256) void scan_kernel(
    const float* __restrict__ scores, int* __restrict__ cnts, int* __restrict__ idx)
{
  const int e = blockIdx.x, tid = threadIdx.x;
  int loc[4], c = 0;
#pragma unroll
  for (int j = 0; j < 4; ++j) {
    int t = tid * 4 + j;
    loc[j] = (scores[t * NE + e] != 0.f) ? 1 : 0;
    c += loc[j];
  }
  __shared__ int sc[256];
  sc[tid] = c;
  __syncthreads();
  for (int off = 1; off < 256; off <<= 1) {
    int v = (tid >= off) ? sc[tid - off] : 0;
    __syncthreads();
    sc[tid] += v;
    __syncthreads();
  }
  int base = sc[tid] - c;
#pragma unroll
  for (int j = 0; j < 4; ++j)
    if (loc[j]) idx[e * T_TOK + base++] = tid * 4 + j;
  if (tid == 255) cnts[e] = sc[255];
}

// ---------------- mxfp4 -> bf16 pre-dequant (memory-bound) ----------------
__global__ __launch_bounds__(256) void dequant_kernel(
    const int* __restrict__ gub, const int* __restrict__ gus,
    const int* __restrict__ dnb, const int* __restrict__ dns,
    ushort* __restrict__ wgu, ushort* __restrict__ wdn)
{
  const int NG = NE * 4096 * 64;
  const int ND = NE * 2048 * 64;
  int tidg = blockIdx.x * 256 + threadIdx.x;
  if (tidg >= NG + ND) return;
  const int* qb; const int* qs; ushort* dst; int bi;
  if (tidg < NG) { bi = tidg; qb = gub; qs = gus; dst = wgu; }
  else           { bi = tidg - NG; qb = dnb; qs = dns; dst = wdn; }
  int sc = qs[bi];
  const int4* bp = (const int4*)(qb + (size_t)bi * 16);
  int4 q0 = bp[0], q1 = bp[1], q2 = bp[2], q3 = bp[3];
  uint w[16];
  w[0]=dq2(q0.x,sc);  w[1]=dq2(q0.y,sc);  w[2]=dq2(q0.z,sc);  w[3]=dq2(q0.w,sc);
  w[4]=dq2(q1.x,sc);  w[5]=dq2(q1.y,sc);  w[6]=dq2(q1.z,sc);  w[7]=dq2(q1.w,sc);
  w[8]=dq2(q2.x,sc);  w[9]=dq2(q2.y,sc);  w[10]=dq2(q2.z,sc); w[11]=dq2(q2.w,sc);
  w[12]=dq2(q3.x,sc); w[13]=dq2(q3.y,sc); w[14]=dq2(q3.z,sc); w[15]=dq2(q3.w,sc);
  uint4* o = (uint4*)(dst + (size_t)bi * 32);
  o[0] = make_uint4(w[0], w[1], w[2], w[3]);
  o[1] = make_uint4(w[4], w[5], w[6], w[7]);
  o[2] = make_uint4(w[8], w[9], w[10], w[11]);
  o[3] = make_uint4(w[12], w[13], w[14], w[15]);
}

// -------- tiled bf16 GEMM, split-precision A (hi+lo), C = A * B^T ----------
// Sparse over routed (token, expert) pairs: M-dim is compacted slots.
// MODE 0: A = gathered t (hi/lo); epilogue GLU+score -> compacted mid (hi/lo)
// MODE 1: A = compacted mid (hi/lo); epilogue scatter atomicAdd to out[tok]
template<int MODE, bool PREDEQ>
__global__ __launch_bounds__(256) void mx_gemm(
    const ushort* __restrict__ Ahi_base,
    const ushort* __restrict__ Alo_base,
    const ushort* __restrict__ Bw,
    const int* __restrict__ qblocks,
    const int* __restrict__ qscales,
    const float* __restrict__ bias,
    const float* __restrict__ scores,
    const int* __restrict__ cnts,
    const int* __restrict__ tokidx,
    ushort* __restrict__ midH,
    ushort* __restrict__ midL,
    float* __restrict__ outp)
{
  constexpr int NTOT = (MODE == 0) ? 2 * DDIM : HDIM;
  constexpr int K    = (MODE == 0) ? HDIM : DDIM;
  const int nt = blockIdx.x, mt = blockIdx.y, e = blockIdx.z;
  const int cnt = cnts[e];
  const int m0 = mt * 128, n0 = nt * 128;
  if (m0 >= cnt) return;
  const size_t aoff = (MODE == 0) ? (size_t)0 : (size_t)e * T_TOK * DDIM;
  const ushort* AH = Ahi_base + aoff;
  const ushort* AL = Alo_base + aoff;

  __shared__ __align__(16) ushort AsH[128 * 64];
  __shared__ __align__(16) ushort AsL[128 * 64];
  __shared__ __align__(16) ushort Bs[128 * 64];
  __shared__ int tok_s[128];

  const int tid = threadIdx.x;
  const int lane = tid & 63;
  const int wv = tid >> 6;
  const int wm = wv >> 1, wn = wv & 1;
  const int fr = lane & 15, kg = lane >> 4;

  if (tid < 128) {
    int sl = m0 + tid;
    tok_s[tid] = (sl < cnt) ? tokidx[e * T_TOK + sl] : 0;
  }
  __syncthreads();

  // per-thread hoisted A-row indices for staging (4 chunks/thread)
  int arow[4];
#pragma unroll
  for (int j = 0; j < 4; ++j) {
    int row = (tid + 256 * j) >> 3;
    arow[j] = (MODE == 0) ? tok_s[row] : (m0 + row);
  }

  f32x4 acc[4][4];
#pragma unroll
  for (int i = 0; i < 4; ++i)
#pragma unroll
    for (int j = 0; j < 4; ++j) acc[i][j] = f32x4{0.f, 0.f, 0.f, 0.f};

  for (int kt = 0; kt < K / 64; ++kt) {
    // stage A hi/lo: global_load_lds, source pre-swizzled (chunk' = chunk ^ (row&7))
#pragma unroll
    for (int j = 0; j < 4; ++j) {
      int cidx = tid + 256 * j;
      int row = cidx >> 3, ck = cidx & 7;
      int sck = ck ^ (row & 7);
      size_t go = (size_t)arow[j] * K + kt * 64 + sck * 8;
      __builtin_amdgcn_global_load_lds((v_g*)(AH + go), (v_l*)((char*)AsH + cidx * 16), 16, 0, 0);
      __builtin_amdgcn_global_load_lds((v_g*)(AL + go), (v_l*)((char*)AsL + cidx * 16), 16, 0, 0);
    }
    if constexpr (PREDEQ) {
#pragma unroll
      for (int j = 0; j < 4; ++j) {
        int cidx = tid + 256 * j;
        int row = cidx >> 3, ck = cidx & 7;
        int sck = ck ^ (row & 7);
        const ushort* g = Bw + ((size_t)e * NTOT + n0 + row) * K + kt * 64 + sck * 8;
        __builtin_amdgcn_global_load_lds((v_g*)g, (v_l*)((char*)Bs + cidx * 16), 16, 0, 0);
      }
    } else {
      const int brow = tid >> 1, bblk = tid & 1;
      int kb = kt * 2 + bblk;
      size_t bi = ((size_t)e * NTOT + n0 + brow) * (K / 32) + kb;
      int sc = qscales[bi];
      const int4* bp = (const int4*)(qblocks + bi * 16);
      int4 q0 = bp[0], q1 = bp[1], q2 = bp[2], q3 = bp[3];
      uint w[16];
      w[0]=dq2(q0.x,sc);  w[1]=dq2(q0.y,sc);  w[2]=dq2(q0.z,sc);  w[3]=dq2(q0.w,sc);
      w[4]=dq2(q1.x,sc);  w[5]=dq2(q1.y,sc);  w[6]=dq2(q1.z,sc);  w[7]=dq2(q1.w,sc);
      w[8]=dq2(q2.x,sc);  w[9]=dq2(q2.y,sc);  w[10]=dq2(q2.z,sc); w[11]=dq2(q2.w,sc);
      w[12]=dq2(q3.x,sc); w[13]=dq2(q3.y,sc); w[14]=dq2(q3.z,sc); w[15]=dq2(q3.w,sc);
#pragma unroll
      for (int q = 0; q < 4; ++q) {
        int ck = bblk * 4 + q;
        int sk = ck ^ (brow & 7);
        *(uint4*)((char*)Bs + brow * 128 + sk * 16) =
            make_uint4(w[4*q], w[4*q+1], w[4*q+2], w[4*q+3]);
      }
    }
    __syncthreads();
#pragma unroll
    for (int kh = 0; kh < 2; ++kh) {
      bf16x8 aH[4], aL[4], bF[4];
#pragma unroll
      for (int mi = 0; mi < 4; ++mi) {
        int r = wm * 64 + mi * 16 + fr;
        int ck = (kh * 4 + kg) ^ (r & 7);
        aH[mi] = *(const bf16x8*)((const char*)AsH + r * 128 + ck * 16);
        aL[mi] = *(const bf16x8*)((const char*)AsL + r * 128 + ck * 16);
      }
#pragma unroll
      for (int ni = 0; ni < 4; ++ni) {
        int r = wn * 64 + ni * 16 + fr;
        int ck = (kh * 4 + kg) ^ (r & 7);
        bF[ni] = *(const bf16x8*)((const char*)Bs + r * 128 + ck * 16);
      }
#pragma unroll
      for (int mi = 0; mi < 4; ++mi)
#pragma unroll
        for (int ni = 0; ni < 4; ++ni) {
          acc[mi][ni] = __builtin_amdgcn_mfma_f32_16x16x32_bf16(aH[mi], bF[ni], acc[mi][ni], 0, 0, 0);
          acc[mi][ni] = __builtin_amdgcn_mfma_f32_16x16x32_bf16(aL[mi], bF[ni], acc[mi][ni], 0, 0, 0);
        }
    }
    __syncthreads();
  }

  const int c = lane & 15, rg = lane >> 4;
  const int sbase = m0 + wm * 64, nbase = n0 + wn * 64;
  if constexpr (MODE == 0) {
#pragma unroll
    for (int mi = 0; mi < 4; ++mi)
#pragma unroll
      for (int ni = 0; ni < 4; ++ni) {
        int n = nbase + ni * 16 + c;
        float bv = bias[(size_t)e * NTOT + n];
#pragma unroll
        for (int r = 0; r < 4; ++r) {
          int slot = sbase + mi * 16 + rg * 4 + r;
          float val = acc[mi][ni][r] + bv;
          float other = __shfl_xor(val, 1);
          if (!(c & 1) && slot < cnt) {
            int tok = tok_s[slot - m0];
            float g = fminf(val, 7.0f);
            float u = fminf(fmaxf(other, -7.0f), 7.0f);
            float glu = g / (1.0f + expf(-1.702f * g));
            float mv = (u + 1.0f) * glu;
            float s = scores[tok * NE + e];
            float m = mv * s;
            ushort hb = f2bf(m);
            size_t idxo = ((size_t)e * T_TOK + slot) * DDIM + ((uint)n >> 1);
            midH[idxo] = hb;
            midL[idxo] = f2bf(m - bf2f(hb));
          }
        }
      }
  } else {
#pragma unroll
    for (int mi = 0; mi < 4; ++mi)
#pragma unroll
      for (int ni = 0; ni < 4; ++ni) {
        int n = nbase + ni * 16 + c;
        float dbv = bias[(size_t)e * NTOT + n];
#pragma unroll
        for (int r = 0; r < 4; ++r) {
          int slot = sbase + mi * 16 + rg * 4 + r;
          if (slot < cnt) {
            int tok = tok_s[slot - m0];
            float s = scores[tok * NE + e];
            atomicAdd(outp + (size_t)tok * HDIM + n, acc[mi][ni][r] + s * dbv);
          }
        }
      }
  }
}

extern "C" void kernel_launch(void* const* d_in, const int* in_sizes, int n_in,
                              void* d_out, int out_size, void* d_ws, size_t ws_size,
                              hipStream_t stream)
{
  const float* x      = (const float*)d_in[0];
  const float* nw     = (const float*)d_in[1];
  const float* rw     = (const float*)d_in[2];
  const float* rb     = (const float*)d_in[3];
  const int*   gus    = (const int*)d_in[4];
  const int*   gub    = (const int*)d_in[5];
  const float* gubias = (const float*)d_in[6];
  const int*   dns    = (const int*)d_in[7];
  const int*   dnb    = (const int*)d_in[8];
  const float* dnbias = (const float*)d_in[9];

  char* ws = (char*)d_ws;
  const size_t SZ_WGU = (size_t)NE * 4096 * 2048 * 2;   // 134 MB
  const size_t SZ_WDN = (size_t)NE * 2048 * 2048 * 2;   //  67 MB
  const size_t SZ_T   = (size_t)T_TOK * HDIM * 2;       //   4 MB (per plane)
  const size_t SZ_MID = (size_t)NE * T_TOK * DDIM * 2;  //  33.5 MB (per plane)
  const size_t SZ_SC  = (size_t)T_TOK * NE * 4;
  const size_t SZ_IDX = (size_t)NE * T_TOK * 4;
  const size_t SZ_CNT = 128;

  const size_t need_act = 2 * SZ_T + 2 * SZ_MID + SZ_SC + SZ_IDX + SZ_CNT;
  const bool predeq = ws_size >= SZ_WGU + SZ_WDN + need_act;
  ushort* wgu = (ushort*)ws;
  ushort* wdn = (ushort*)(ws + SZ_WGU);
  char* base2 = predeq ? (ws + SZ_WGU + SZ_WDN) : ws;
  ushort* thi    = (ushort*)base2;
  ushort* tlo    = (ushort*)(base2 + SZ_T);
  ushort* midHp  = (ushort*)(base2 + 2 * SZ_T);
  ushort* midLp  = (ushort*)(base2 + 2 * SZ_T + SZ_MID);
  float*  scores = (float*)(base2 + 2 * SZ_T + 2 * SZ_MID);
  int*    cnts   = (int*)(base2 + 2 * SZ_T + 2 * SZ_MID + SZ_SC);
  int*    tokidx = (int*)(base2 + 2 * SZ_T + 2 * SZ_MID + SZ_SC + SZ_CNT);
  float*  outp   = (float*)d_out;

  router_kernel<<<T_TOK, 256, 0, stream>>>(x, nw, rw, rb, thi, tlo, scores);
  hipMemcpyAsync(d_out, (void*)x, (size_t)T_TOK * HDIM * 4, hipMemcpyDeviceToDevice, stream);
  scan_kernel<<<NE, 256, 0, stream>>>(scores, cnts, tokidx);
  if (predeq) {
    dequant_kernel<<<(NE * 4096 * 64 + NE * 2048 * 64) / 256, 256, 0, stream>>>(
        gub, gus, dnb, dns, wgu, wdn);
    mx_gemm<0, true><<<dim3(32, 8, NE), 256, 0, stream>>>(
        thi, tlo, wgu, nullptr, nullptr, gubias, scores, cnts, tokidx, midHp, midLp, nullptr);
    mx_gemm<1, true><<<dim3(16, 8, NE), 256, 0, stream>>>(
        midHp, midLp, wdn, nullptr, nullptr, dnbias, scores, cnts, tokidx, nullptr, nullptr, outp);
  } else {
    mx_gemm<0, false><<<dim3(32, 8, NE), 256, 0, stream>>>(
        thi, tlo, nullptr, gub, gus, gubias, scores, cnts, tokidx, midHp, midLp, nullptr);
    mx_gemm<1, false><<<dim3(16, 8, NE), 256, 0, stream>>>(
        midHp, midLp, nullptr, dnb, dns, dnbias, scores, cnts, tokidx, nullptr, nullptr, outp);
  }
}

// Round 5
// 443.559 us; speedup vs baseline: 1.2887x; 1.0762x over previous
//
#include <hip/hip_runtime.h>
#include <hip/hip_bf16.h>
#include <stdint.h>

#define T_TOK 1024
#define HDIM 2048
#define DDIM 2048
#define NE 8

typedef unsigned int uint;
typedef unsigned short ushort;

typedef __bf16 bf16x8 __attribute__((ext_vector_type(8)));
typedef float f32x4 __attribute__((ext_vector_type(4)));

typedef __attribute__((address_space(1))) const void v_g;
typedef __attribute__((address_space(3))) void v_l;

__device__ __forceinline__ ushort f2bf(float f) {
  uint u = __float_as_uint(f);
  u += 0x7fffu + ((u >> 16) & 1u);
  return (ushort)(u >> 16);
}
__device__ __forceinline__ float bf2f(ushort b) {
  uint u = (uint)b << 16;
  return __uint_as_float(u);
}

// e2m1 nibble * 2^(sc-127) -> bf16 bits (exact; flush exp<=0 to signed zero)
__device__ __forceinline__ uint dq1(uint nib, int sc) {
  uint m = nib & 7u;
  int e = (int)(m >> 1);
  int be = sc + e - 1;
  uint mant = (e != 0) ? ((m & 1u) << 6) : 0u;
  uint r = ((m != 0u) && (be > 0)) ? (((uint)be << 7) | mant) : 0u;
  return r | ((nib & 8u) << 12);
}
__device__ __forceinline__ uint dq2(uint b, int sc) {
  return dq1(b & 15u, sc) | (dq1((b >> 4) & 15u, sc) << 16);
}

// ---------------- RMSNorm + router (f32 logits, top-4 softmax) ----------------
__global__ __launch_bounds__(256) void router_kernel(
    const float* __restrict__ x, const float* __restrict__ nw,
    const float* __restrict__ rw, const float* __restrict__ rb,
    ushort* __restrict__ thi, ushort* __restrict__ tlo, float* __restrict__ scores)
{
  const int t = blockIdx.x, tid = threadIdx.x;
  const float4* xr = (const float4*)(x + (size_t)t * HDIM);
  float4 v0 = xr[tid * 2], v1 = xr[tid * 2 + 1];
  float ss = v0.x*v0.x + v0.y*v0.y + v0.z*v0.z + v0.w*v0.w
           + v1.x*v1.x + v1.y*v1.y + v1.z*v1.z + v1.w*v1.w;
  __shared__ float red[256];
  red[tid] = ss;
  __syncthreads();
  for (int s = 128; s > 0; s >>= 1) {
    if (tid < s) red[tid] += red[tid + s];
    __syncthreads();
  }
  const float rstd = rsqrtf(red[0] * (1.0f / HDIM) + 1e-5f);
  float xv[8] = {v0.x, v0.y, v0.z, v0.w, v1.x, v1.y, v1.z, v1.w};
  float lp[NE];
#pragma unroll
  for (int e = 0; e < NE; ++e) lp[e] = 0.f;
  union { ushort us[8]; uint4 v; } pkh, pkl;
  const int h0 = tid * 8;
#pragma unroll
  for (int j = 0; j < 8; ++j) {
    int h = h0 + j;
    float tn = xv[j] * rstd * nw[h];
    ushort hb = f2bf(tn);
    pkh.us[j] = hb;
    pkl.us[j] = f2bf(tn - bf2f(hb));
#pragma unroll
    for (int e = 0; e < NE; ++e) lp[e] += tn * rw[h * NE + e];
  }
  *(uint4*)(thi + (size_t)t * HDIM + h0) = pkh.v;
  *(uint4*)(tlo + (size_t)t * HDIM + h0) = pkl.v;
#pragma unroll
  for (int e = 0; e < NE; ++e)
#pragma unroll
    for (int off = 32; off > 0; off >>= 1) lp[e] += __shfl_down(lp[e], off);
  __shared__ float wred[4][NE];
  if ((tid & 63) == 0) {
#pragma unroll
    for (int e = 0; e < NE; ++e) wred[tid >> 6][e] = lp[e];
  }
  __syncthreads();
  if (tid == 0) {
    float lg[NE];
#pragma unroll
    for (int e = 0; e < NE; ++e)
      lg[e] = wred[0][e] + wred[1][e] + wred[2][e] + wred[3][e] + rb[e];
    bool used[NE] = {false, false, false, false, false, false, false, false};
    float tv[4]; int ti[4];
    for (int s = 0; s < 4; ++s) {          // ties: lowest index first (strict >)
      float best = -3.4e38f; int bi = 0;
      for (int e = 0; e < NE; ++e)
        if (!used[e] && lg[e] > best) { best = lg[e]; bi = e; }
      used[bi] = true; tv[s] = best; ti[s] = bi;
    }
    float den = 0.f, ev[4];
    for (int s = 0; s < 4; ++s) { ev[s] = expf(tv[s] - tv[0]); den += ev[s]; }
    float so[NE] = {0, 0, 0, 0, 0, 0, 0, 0};
    for (int s = 0; s < 4; ++s) so[ti[s]] = ev[s] / den;
#pragma unroll
    for (int e = 0; e < NE; ++e) scores[t * NE + e] = so[e];
  }
}

// ------------- per-expert token compaction (deterministic prefix scan) --------
__global__ __launch_bounds__(256) void scan_kernel(
    const float* __restrict__ scores, int* __restrict__ cnts, int* __restrict__ idx)
{
  const int e = blockIdx.x, tid = threadIdx.x;
  int loc[4], c = 0;
#pragma unroll
  for (int j = 0; j < 4; ++j) {
    int t = tid * 4 + j;
    loc[j] = (scores[t * NE + e] != 0.f) ? 1 : 0;
    c += loc[j];
  }
  __shared__ int sc[256];
  sc[tid] = c;
  __syncthreads();
  for (int off = 1; off < 256; off <<= 1) {
    int v = (tid >= off) ? sc[tid - off] : 0;
    __syncthreads();
    sc[tid] += v;
    __syncthreads();
  }
  int base = sc[tid] - c;
#pragma unroll
  for (int j = 0; j < 4; ++j)
    if (loc[j]) idx[e * T_TOK + base++] = tid * 4 + j;
  if (tid == 255) cnts[e] = sc[255];
}

// ---------------- mxfp4 -> bf16 pre-dequant (memory-bound) ----------------
__global__ __launch_bounds__(256) void dequant_kernel(
    const int* __restrict__ gub, const int* __restrict__ gus,
    const int* __restrict__ dnb, const int* __restrict__ dns,
    ushort* __restrict__ wgu, ushort* __restrict__ wdn)
{
  const int NG = NE * 4096 * 64;
  const int ND = NE * 2048 * 64;
  int tidg = blockIdx.x * 256 + threadIdx.x;
  if (tidg >= NG + ND) return;
  const int* qb; const int* qs; ushort* dst; int bi;
  if (tidg < NG) { bi = tidg; qb = gub; qs = gus; dst = wgu; }
  else           { bi = tidg - NG; qb = dnb; qs = dns; dst = wdn; }
  int sc = qs[bi];
  const int4* bp = (const int4*)(qb + (size_t)bi * 16);
  int4 q0 = bp[0], q1 = bp[1], q2 = bp[2], q3 = bp[3];
  uint w[16];
  w[0]=dq2(q0.x,sc);  w[1]=dq2(q0.y,sc);  w[2]=dq2(q0.z,sc);  w[3]=dq2(q0.w,sc);
  w[4]=dq2(q1.x,sc);  w[5]=dq2(q1.y,sc);  w[6]=dq2(q1.z,sc);  w[7]=dq2(q1.w,sc);
  w[8]=dq2(q2.x,sc);  w[9]=dq2(q2.y,sc);  w[10]=dq2(q2.z,sc); w[11]=dq2(q2.w,sc);
  w[12]=dq2(q3.x,sc); w[13]=dq2(q3.y,sc); w[14]=dq2(q3.z,sc); w[15]=dq2(q3.w,sc);
  uint4* o = (uint4*)(dst + (size_t)bi * 32);
  o[0] = make_uint4(w[0], w[1], w[2], w[3]);
  o[1] = make_uint4(w[4], w[5], w[6], w[7]);
  o[2] = make_uint4(w[8], w[9], w[10], w[11]);
  o[3] = make_uint4(w[12], w[13], w[14], w[15]);
}

// -------- tiled bf16 GEMM, optional split-precision A (hi+lo), C = A * B^T ----
// Sparse over routed (token, expert) pairs: M-dim is compacted slots.
// MODE 0 (SPLITA=true):  A = gathered t (hi+lo); GLU+score -> compacted mid (single bf16)
// MODE 1 (SPLITA=false): A = compacted mid; scatter atomicAdd to out[tok]
template<int MODE, bool PREDEQ, bool SPLITA>
__global__ __launch_bounds__(256) void mx_gemm(
    const ushort* __restrict__ Ahi_base,
    const ushort* __restrict__ Alo_base,
    const ushort* __restrict__ Bw,
    const int* __restrict__ qblocks,
    const int* __restrict__ qscales,
    const float* __restrict__ bias,
    const float* __restrict__ scores,
    const int* __restrict__ cnts,
    const int* __restrict__ tokidx,
    ushort* __restrict__ midH,
    float* __restrict__ outp)
{
  constexpr int NTOT = (MODE == 0) ? 2 * DDIM : HDIM;
  constexpr int K    = (MODE == 0) ? HDIM : DDIM;
  const int nt = blockIdx.x, mt = blockIdx.y, e = blockIdx.z;
  const int cnt = cnts[e];
  const int m0 = mt * 128, n0 = nt * 128;
  if (m0 >= cnt) return;
  const size_t aoff = (MODE == 0) ? (size_t)0 : (size_t)e * T_TOK * DDIM;
  const ushort* AH = Ahi_base + aoff;
  const ushort* AL = Alo_base + aoff;

  __shared__ __align__(16) ushort AsH[128 * 64];
  __shared__ __align__(16) ushort AsL[SPLITA ? 128 * 64 : 8];
  __shared__ __align__(16) ushort Bs[128 * 64];
  __shared__ int tok_s[128];

  const int tid = threadIdx.x;
  const int lane = tid & 63;
  const int wv = tid >> 6;
  const int wm = wv >> 1, wn = wv & 1;
  const int fr = lane & 15, kg = lane >> 4;

  if (tid < 128) {
    int sl = m0 + tid;
    tok_s[tid] = (sl < cnt) ? tokidx[e * T_TOK + sl] : 0;
  }
  __syncthreads();

  // per-thread hoisted A-row indices for staging (4 chunks/thread)
  int arow[4];
#pragma unroll
  for (int j = 0; j < 4; ++j) {
    int row = (tid + 256 * j) >> 3;
    arow[j] = (MODE == 0) ? tok_s[row] : (m0 + row);
  }

  f32x4 acc[4][4];
#pragma unroll
  for (int i = 0; i < 4; ++i)
#pragma unroll
    for (int j = 0; j < 4; ++j) acc[i][j] = f32x4{0.f, 0.f, 0.f, 0.f};

  for (int kt = 0; kt < K / 64; ++kt) {
    // stage A (hi [+lo]): global_load_lds, source pre-swizzled (chunk' = chunk ^ (row&7))
#pragma unroll
    for (int j = 0; j < 4; ++j) {
      int cidx = tid + 256 * j;
      int row = cidx >> 3, ck = cidx & 7;
      int sck = ck ^ (row & 7);
      size_t go = (size_t)arow[j] * K + kt * 64 + sck * 8;
      __builtin_amdgcn_global_load_lds((v_g*)(AH + go), (v_l*)((char*)AsH + cidx * 16), 16, 0, 0);
      if constexpr (SPLITA)
        __builtin_amdgcn_global_load_lds((v_g*)(AL + go), (v_l*)((char*)AsL + cidx * 16), 16, 0, 0);
    }
    if constexpr (PREDEQ) {
#pragma unroll
      for (int j = 0; j < 4; ++j) {
        int cidx = tid + 256 * j;
        int row = cidx >> 3, ck = cidx & 7;
        int sck = ck ^ (row & 7);
        const ushort* g = Bw + ((size_t)e * NTOT + n0 + row) * K + kt * 64 + sck * 8;
        __builtin_amdgcn_global_load_lds((v_g*)g, (v_l*)((char*)Bs + cidx * 16), 16, 0, 0);
      }
    } else {
      const int brow = tid >> 1, bblk = tid & 1;
      int kb = kt * 2 + bblk;
      size_t bi = ((size_t)e * NTOT + n0 + brow) * (K / 32) + kb;
      int sc = qscales[bi];
      const int4* bp = (const int4*)(qblocks + bi * 16);
      int4 q0 = bp[0], q1 = bp[1], q2 = bp[2], q3 = bp[3];
      uint w[16];
      w[0]=dq2(q0.x,sc);  w[1]=dq2(q0.y,sc);  w[2]=dq2(q0.z,sc);  w[3]=dq2(q0.w,sc);
      w[4]=dq2(q1.x,sc);  w[5]=dq2(q1.y,sc);  w[6]=dq2(q1.z,sc);  w[7]=dq2(q1.w,sc);
      w[8]=dq2(q2.x,sc);  w[9]=dq2(q2.y,sc);  w[10]=dq2(q2.z,sc); w[11]=dq2(q2.w,sc);
      w[12]=dq2(q3.x,sc); w[13]=dq2(q3.y,sc); w[14]=dq2(q3.z,sc); w[15]=dq2(q3.w,sc);
#pragma unroll
      for (int q = 0; q < 4; ++q) {
        int ck = bblk * 4 + q;
        int sk = ck ^ (brow & 7);
        *(uint4*)((char*)Bs + brow * 128 + sk * 16) =
            make_uint4(w[4*q], w[4*q+1], w[4*q+2], w[4*q+3]);
      }
    }
    __syncthreads();
#pragma unroll
    for (int kh = 0; kh < 2; ++kh) {
      bf16x8 aH[4], aL[4], bF[4];
#pragma unroll
      for (int mi = 0; mi < 4; ++mi) {
        int r = wm * 64 + mi * 16 + fr;
        int ck = (kh * 4 + kg) ^ (r & 7);
        aH[mi] = *(const bf16x8*)((const char*)AsH + r * 128 + ck * 16);
        if constexpr (SPLITA)
          aL[mi] = *(const bf16x8*)((const char*)AsL + r * 128 + ck * 16);
      }
#pragma unroll
      for (int ni = 0; ni < 4; ++ni) {
        int r = wn * 64 + ni * 16 + fr;
        int ck = (kh * 4 + kg) ^ (r & 7);
        bF[ni] = *(const bf16x8*)((const char*)Bs + r * 128 + ck * 16);
      }
#pragma unroll
      for (int mi = 0; mi < 4; ++mi)
#pragma unroll
        for (int ni = 0; ni < 4; ++ni) {
          acc[mi][ni] = __builtin_amdgcn_mfma_f32_16x16x32_bf16(aH[mi], bF[ni], acc[mi][ni], 0, 0, 0);
          if constexpr (SPLITA)
            acc[mi][ni] = __builtin_amdgcn_mfma_f32_16x16x32_bf16(aL[mi], bF[ni], acc[mi][ni], 0, 0, 0);
        }
    }
    __syncthreads();
  }

  const int c = lane & 15, rg = lane >> 4;
  const int sbase = m0 + wm * 64, nbase = n0 + wn * 64;
  if constexpr (MODE == 0) {
#pragma unroll
    for (int mi = 0; mi < 4; ++mi)
#pragma unroll
      for (int ni = 0; ni < 4; ++ni) {
        int n = nbase + ni * 16 + c;
        float bv = bias[(size_t)e * NTOT + n];
#pragma unroll
        for (int r = 0; r < 4; ++r) {
          int slot = sbase + mi * 16 + rg * 4 + r;
          float val = acc[mi][ni][r] + bv;
          float other = __shfl_xor(val, 1);
          if (!(c & 1) && slot < cnt) {
            int tok = tok_s[slot - m0];
            float g = fminf(val, 7.0f);
            float u = fminf(fmaxf(other, -7.0f), 7.0f);
            float glu = g / (1.0f + expf(-1.702f * g));
            float mv = (u + 1.0f) * glu;
            float s = scores[tok * NE + e];
            midH[((size_t)e * T_TOK + slot) * DDIM + ((uint)n >> 1)] = f2bf(mv * s);
          }
        }
      }
  } else {
#pragma unroll
    for (int mi = 0; mi < 4; ++mi)
#pragma unroll
      for (int ni = 0; ni < 4; ++ni) {
        int n = nbase + ni * 16 + c;
        float dbv = bias[(size_t)e * NTOT + n];
#pragma unroll
        for (int r = 0; r < 4; ++r) {
          int slot = sbase + mi * 16 + rg * 4 + r;
          if (slot < cnt) {
            int tok = tok_s[slot - m0];
            float s = scores[tok * NE + e];
            atomicAdd(outp + (size_t)tok * HDIM + n, acc[mi][ni][r] + s * dbv);
          }
        }
      }
  }
}

extern "C" void kernel_launch(void* const* d_in, const int* in_sizes, int n_in,
                              void* d_out, int out_size, void* d_ws, size_t ws_size,
                              hipStream_t stream)
{
  const float* x      = (const float*)d_in[0];
  const float* nw     = (const float*)d_in[1];
  const float* rw     = (const float*)d_in[2];
  const float* rb     = (const float*)d_in[3];
  const int*   gus    = (const int*)d_in[4];
  const int*   gub    = (const int*)d_in[5];
  const float* gubias = (const float*)d_in[6];
  const int*   dns    = (const int*)d_in[7];
  const int*   dnb    = (const int*)d_in[8];
  const float* dnbias = (const float*)d_in[9];

  char* ws = (char*)d_ws;
  const size_t SZ_WGU = (size_t)NE * 4096 * 2048 * 2;   // 134 MB
  const size_t SZ_WDN = (size_t)NE * 2048 * 2048 * 2;   //  67 MB
  const size_t SZ_T   = (size_t)T_TOK * HDIM * 2;       //   4 MB (per plane)
  const size_t SZ_MID = (size_t)NE * T_TOK * DDIM * 2;  //  33.5 MB
  const size_t SZ_SC  = (size_t)T_TOK * NE * 4;
  const size_t SZ_IDX = (size_t)NE * T_TOK * 4;
  const size_t SZ_CNT = 128;

  const size_t need_act = 2 * SZ_T + SZ_MID + SZ_SC + SZ_IDX + SZ_CNT;
  const bool predeq = ws_size >= SZ_WGU + SZ_WDN + need_act;
  ushort* wgu = (ushort*)ws;
  ushort* wdn = (ushort*)(ws + SZ_WGU);
  char* base2 = predeq ? (ws + SZ_WGU + SZ_WDN) : ws;
  ushort* thi    = (ushort*)base2;
  ushort* tlo    = (ushort*)(base2 + SZ_T);
  ushort* midHp  = (ushort*)(base2 + 2 * SZ_T);
  float*  scores = (float*)(base2 + 2 * SZ_T + SZ_MID);
  int*    cnts   = (int*)(base2 + 2 * SZ_T + SZ_MID + SZ_SC);
  int*    tokidx = (int*)(base2 + 2 * SZ_T + SZ_MID + SZ_SC + SZ_CNT);
  float*  outp   = (float*)d_out;

  router_kernel<<<T_TOK, 256, 0, stream>>>(x, nw, rw, rb, thi, tlo, scores);
  hipMemcpyAsync(d_out, (void*)x, (size_t)T_TOK * HDIM * 4, hipMemcpyDeviceToDevice, stream);
  scan_kernel<<<NE, 256, 0, stream>>>(scores, cnts, tokidx);
  if (predeq) {
    dequant_kernel<<<(NE * 4096 * 64 + NE * 2048 * 64) / 256, 256, 0, stream>>>(
        gub, gus, dnb, dns, wgu, wdn);
    mx_gemm<0, true, true><<<dim3(32, 8, NE), 256, 0, stream>>>(
        thi, tlo, wgu, nullptr, nullptr, gubias, scores, cnts, tokidx, midHp, nullptr);
    mx_gemm<1, true, false><<<dim3(16, 8, NE), 256, 0, stream>>>(
        midHp, nullptr, wdn, nullptr, nullptr, dnbias, scores, cnts, tokidx, nullptr, outp);
  } else {
    mx_gemm<0, false, true><<<dim3(32, 8, NE), 256, 0, stream>>>(
        thi, tlo, nullptr, gub, gus, gubias, scores, cnts, tokidx, midHp, nullptr);
    mx_gemm<1, false, false><<<dim3(16, 8, NE), 256, 0, stream>>>(
        midHp, nullptr, nullptr, dnb, dns, dnbias, scores, cnts, tokidx, nullptr, outp);
  }
}

// Round 6
// 430.214 us; speedup vs baseline: 1.3287x; 1.0310x over previous
//
#include <hip/hip_runtime.h>
#include <hip/hip_bf16.h>
#include <stdint.h>

#define T_TOK 1024
#define HDIM 2048
#define DDIM 2048
#define NE 8

typedef unsigned int uint;
typedef unsigned short ushort;

typedef __bf16 bf16x8 __attribute__((ext_vector_type(8)));
typedef float f32x4 __attribute__((ext_vector_type(4)));

typedef __attribute__((address_space(1))) const void v_g;
typedef __attribute__((address_space(3))) void v_l;

__device__ __forceinline__ ushort f2bf(float f) {
  uint u = __float_as_uint(f);
  u += 0x7fffu + ((u >> 16) & 1u);
  return (ushort)(u >> 16);
}
__device__ __forceinline__ float bf2f(ushort b) {
  uint u = (uint)b << 16;
  return __uint_as_float(u);
}

// e2m1 nibble * 2^(sc-127) -> bf16 bits (exact; flush exp<=0 to signed zero)
__device__ __forceinline__ uint dq1(uint nib, int sc) {
  uint m = nib & 7u;
  int e = (int)(m >> 1);
  int be = sc + e - 1;
  uint mant = (e != 0) ? ((m & 1u) << 6) : 0u;
  uint r = ((m != 0u) && (be > 0)) ? (((uint)be << 7) | mant) : 0u;
  return r | ((nib & 8u) << 12);
}
__device__ __forceinline__ uint dq2(uint b, int sc) {
  return dq1(b & 15u, sc) | (dq1((b >> 4) & 15u, sc) << 16);
}

// ---------------- RMSNorm + router (f32 logits, top-4 softmax) ----------------
__global__ __launch_bounds__(256) void router_kernel(
    const float* __restrict__ x, const float* __restrict__ nw,
    const float* __restrict__ rw, const float* __restrict__ rb,
    ushort* __restrict__ thi, ushort* __restrict__ tlo, float* __restrict__ scores)
{
  const int t = blockIdx.x, tid = threadIdx.x;
  const float4* xr = (const float4*)(x + (size_t)t * HDIM);
  float4 v0 = xr[tid * 2], v1 = xr[tid * 2 + 1];
  float ss = v0.x*v0.x + v0.y*v0.y + v0.z*v0.z + v0.w*v0.w
           + v1.x*v1.x + v1.y*v1.y + v1.z*v1.z + v1.w*v1.w;
  __shared__ float red[256];
  red[tid] = ss;
  __syncthreads();
  for (int s = 128; s > 0; s >>= 1) {
    if (tid < s) red[tid] += red[tid + s];
    __syncthreads();
  }
  const float rstd = rsqrtf(red[0] * (1.0f / HDIM) + 1e-5f);
  float xv[8] = {v0.x, v0.y, v0.z, v0.w, v1.x, v1.y, v1.z, v1.w};
  float lp[NE];
#pragma unroll
  for (int e = 0; e < NE; ++e) lp[e] = 0.f;
  union { ushort us[8]; uint4 v; } pkh, pkl;
  const int h0 = tid * 8;
#pragma unroll
  for (int j = 0; j < 8; ++j) {
    int h = h0 + j;
    float tn = xv[j] * rstd * nw[h];
    ushort hb = f2bf(tn);
    pkh.us[j] = hb;
    pkl.us[j] = f2bf(tn - bf2f(hb));
#pragma unroll
    for (int e = 0; e < NE; ++e) lp[e] += tn * rw[h * NE + e];
  }
  *(uint4*)(thi + (size_t)t * HDIM + h0) = pkh.v;
  *(uint4*)(tlo + (size_t)t * HDIM + h0) = pkl.v;
#pragma unroll
  for (int e = 0; e < NE; ++e)
#pragma unroll
    for (int off = 32; off > 0; off >>= 1) lp[e] += __shfl_down(lp[e], off);
  __shared__ float wred[4][NE];
  if ((tid & 63) == 0) {
#pragma unroll
    for (int e = 0; e < NE; ++e) wred[tid >> 6][e] = lp[e];
  }
  __syncthreads();
  if (tid == 0) {
    float lg[NE];
#pragma unroll
    for (int e = 0; e < NE; ++e)
      lg[e] = wred[0][e] + wred[1][e] + wred[2][e] + wred[3][e] + rb[e];
    bool used[NE] = {false, false, false, false, false, false, false, false};
    float tv[4]; int ti[4];
    for (int s = 0; s < 4; ++s) {          // ties: lowest index first (strict >)
      float best = -3.4e38f; int bi = 0;
      for (int e = 0; e < NE; ++e)
        if (!used[e] && lg[e] > best) { best = lg[e]; bi = e; }
      used[bi] = true; tv[s] = best; ti[s] = bi;
    }
    float den = 0.f, ev[4];
    for (int s = 0; s < 4; ++s) { ev[s] = expf(tv[s] - tv[0]); den += ev[s]; }
    float so[NE] = {0, 0, 0, 0, 0, 0, 0, 0};
    for (int s = 0; s < 4; ++s) so[ti[s]] = ev[s] / den;
#pragma unroll
    for (int e = 0; e < NE; ++e) scores[t * NE + e] = so[e];
  }
}

// ------------- per-expert token compaction (deterministic prefix scan) --------
__global__ __launch_bounds__(256) void scan_kernel(
    const float* __restrict__ scores, int* __restrict__ cnts, int* __restrict__ idx)
{
  const int e = blockIdx.x, tid = threadIdx.x;
  int loc[4], c = 0;
#pragma unroll
  for (int j = 0; j < 4; ++j) {
    int t = tid * 4 + j;
    loc[j] = (scores[t * NE + e] != 0.f) ? 1 : 0;
    c += loc[j];
  }
  __shared__ int sc[256];
  sc[tid] = c;
  __syncthreads();
  for (int off = 1; off < 256; off <<= 1) {
    int v = (tid >= off) ? sc[tid - off] : 0;
    __syncthreads();
    sc[tid] += v;
    __syncthreads();
  }
  int base = sc[tid] - c;
#pragma unroll
  for (int j = 0; j < 4; ++j)
    if (loc[j]) idx[e * T_TOK + base++] = tid * 4 + j;
  if (tid == 255) cnts[e] = sc[255];
}

// ---------------- mxfp4 -> bf16 pre-dequant (memory-bound) ----------------
__global__ __launch_bounds__(256) void dequant_kernel(
    const int* __restrict__ gub, const int* __restrict__ gus,
    const int* __restrict__ dnb, const int* __restrict__ dns,
    ushort* __restrict__ wgu, ushort* __restrict__ wdn)
{
  const int NG = NE * 4096 * 64;
  const int ND = NE * 2048 * 64;
  int tidg = blockIdx.x * 256 + threadIdx.x;
  if (tidg >= NG + ND) return;
  const int* qb; const int* qs; ushort* dst; int bi;
  if (tidg < NG) { bi = tidg; qb = gub; qs = gus; dst = wgu; }
  else           { bi = tidg - NG; qb = dnb; qs = dns; dst = wdn; }
  int sc = qs[bi];
  const int4* bp = (const int4*)(qb + (size_t)bi * 16);
  int4 q0 = bp[0], q1 = bp[1], q2 = bp[2], q3 = bp[3];
  uint w[16];
  w[0]=dq2(q0.x,sc);  w[1]=dq2(q0.y,sc);  w[2]=dq2(q0.z,sc);  w[3]=dq2(q0.w,sc);
  w[4]=dq2(q1.x,sc);  w[5]=dq2(q1.y,sc);  w[6]=dq2(q1.z,sc);  w[7]=dq2(q1.w,sc);
  w[8]=dq2(q2.x,sc);  w[9]=dq2(q2.y,sc);  w[10]=dq2(q2.z,sc); w[11]=dq2(q2.w,sc);
  w[12]=dq2(q3.x,sc); w[13]=dq2(q3.y,sc); w[14]=dq2(q3.z,sc); w[15]=dq2(q3.w,sc);
  uint4* o = (uint4*)(dst + (size_t)bi * 32);
  o[0] = make_uint4(w[0], w[1], w[2], w[3]);
  o[1] = make_uint4(w[4], w[5], w[6], w[7]);
  o[2] = make_uint4(w[8], w[9], w[10], w[11]);
  o[3] = make_uint4(w[12], w[13], w[14], w[15]);
}

// -------- tiled bf16 GEMM, 2-phase double-buffered (T3), BK=32 ----------------
// C = A * B^T over routed (token, expert) pairs; 128x128 tile.
// MODE 0 (SPLITA=true):  A = gathered t (hi+lo); GLU+score -> compacted mid bf16
// MODE 1 (SPLITA=false): A = compacted mid; scatter atomicAdd to out[tok]
// LDS swizzle: chunk' = chunk ^ ((row>>1)&3) on 16B chunks of 64B rows
// (bijective per row; 16-lane column reads land 2 lanes/bank = free).
template<int MODE, bool PREDEQ, bool SPLITA>
__global__ __launch_bounds__(256) void mx_gemm(
    const ushort* __restrict__ Ahi_base,
    const ushort* __restrict__ Alo_base,
    const ushort* __restrict__ Bw,
    const int* __restrict__ qblocks,
    const int* __restrict__ qscales,
    const float* __restrict__ bias,
    const float* __restrict__ scores,
    const int* __restrict__ cnts,
    const int* __restrict__ tokidx,
    ushort* __restrict__ midH,
    float* __restrict__ outp)
{
  constexpr int NTOT = (MODE == 0) ? 2 * DDIM : HDIM;
  constexpr int K    = (MODE == 0) ? HDIM : DDIM;
  constexpr int NKT  = K / 32;
  const int nt = blockIdx.x, mt = blockIdx.y, e = blockIdx.z;
  const int cnt = cnts[e];
  const int m0 = mt * 128, n0 = nt * 128;
  if (m0 >= cnt) return;
  const size_t aoff = (MODE == 0) ? (size_t)0 : (size_t)e * T_TOK * DDIM;
  const ushort* AH = Ahi_base + aoff;
  const ushort* AL = Alo_base + aoff;

  __shared__ __align__(16) ushort AsH[2][128 * 32];
  __shared__ __align__(16) ushort AsL[SPLITA ? 2 : 1][SPLITA ? 128 * 32 : 8];
  __shared__ __align__(16) ushort Bs[2][128 * 32];
  __shared__ int tok_s[128];

  const int tid = threadIdx.x;
  const int lane = tid & 63;
  const int wv = tid >> 6;
  const int wm = wv >> 1, wn = wv & 1;
  const int fr = lane & 15, kg = lane >> 4;

  if (tid < 128) {
    int sl = m0 + tid;
    tok_s[tid] = (sl < cnt) ? tokidx[e * T_TOK + sl] : 0;
  }
  __syncthreads();

  // per-thread hoisted A-row indices for staging (2 chunks/thread)
  int arow[2];
#pragma unroll
  for (int j = 0; j < 2; ++j) {
    int row = (tid + 256 * j) >> 2;
    arow[j] = (MODE == 0) ? tok_s[row] : (m0 + row);
  }

  f32x4 acc[4][4];
#pragma unroll
  for (int i = 0; i < 4; ++i)
#pragma unroll
    for (int j = 0; j < 4; ++j) acc[i][j] = f32x4{0.f, 0.f, 0.f, 0.f};

  auto do_stage = [&](int buf, int kt) {
#pragma unroll
    for (int j = 0; j < 2; ++j) {
      int cidx = tid + 256 * j;
      int row = cidx >> 2, ck = cidx & 3;
      int gck = ck ^ ((row >> 1) & 3);
      size_t go = (size_t)arow[j] * K + kt * 32 + gck * 8;
      __builtin_amdgcn_global_load_lds((v_g*)(AH + go),
          (v_l*)((char*)&AsH[buf][0] + cidx * 16), 16, 0, 0);
      if constexpr (SPLITA)
        __builtin_amdgcn_global_load_lds((v_g*)(AL + go),
            (v_l*)((char*)&AsL[buf][0] + cidx * 16), 16, 0, 0);
    }
    if constexpr (PREDEQ) {
#pragma unroll
      for (int j = 0; j < 2; ++j) {
        int cidx = tid + 256 * j;
        int row = cidx >> 2, ck = cidx & 3;
        int gck = ck ^ ((row >> 1) & 3);
        const ushort* g = Bw + ((size_t)e * NTOT + n0 + row) * K + kt * 32 + gck * 8;
        __builtin_amdgcn_global_load_lds((v_g*)g,
            (v_l*)((char*)&Bs[buf][0] + cidx * 16), 16, 0, 0);
      }
    } else {
      const int brow = tid >> 1, half = tid & 1;
      size_t bi = ((size_t)e * NTOT + n0 + brow) * (K / 32) + kt;
      int sc = qscales[bi];
      const int4* bp = (const int4*)(qblocks + bi * 16) + half * 2;
      int4 q0 = bp[0], q1 = bp[1];
      uint w[8];
      w[0]=dq2(q0.x,sc); w[1]=dq2(q0.y,sc); w[2]=dq2(q0.z,sc); w[3]=dq2(q0.w,sc);
      w[4]=dq2(q1.x,sc); w[5]=dq2(q1.y,sc); w[6]=dq2(q1.z,sc); w[7]=dq2(q1.w,sc);
      int s = (brow >> 1) & 3;
#pragma unroll
      for (int q = 0; q < 2; ++q) {
        int gc = half * 2 + q;
        int ckk = gc ^ s;
        *(uint4*)((char*)&Bs[buf][0] + brow * 64 + ckk * 16) =
            make_uint4(w[4*q], w[4*q+1], w[4*q+2], w[4*q+3]);
      }
    }
  };

  auto do_compute = [&](int buf) {
    bf16x8 aH[4], aL[4], bF[4];
#pragma unroll
    for (int mi = 0; mi < 4; ++mi) {
      int r = wm * 64 + mi * 16 + fr;
      int ck = kg ^ ((r >> 1) & 3);
      aH[mi] = *(const bf16x8*)(&AsH[buf][r * 32 + ck * 8]);
      if constexpr (SPLITA)
        aL[mi] = *(const bf16x8*)(&AsL[buf][r * 32 + ck * 8]);
    }
#pragma unroll
    for (int ni = 0; ni < 4; ++ni) {
      int r = wn * 64 + ni * 16 + fr;
      int ck = kg ^ ((r >> 1) & 3);
      bF[ni] = *(const bf16x8*)(&Bs[buf][r * 32 + ck * 8]);
    }
#pragma unroll
    for (int mi = 0; mi < 4; ++mi)
#pragma unroll
      for (int ni = 0; ni < 4; ++ni) {
        acc[mi][ni] = __builtin_amdgcn_mfma_f32_16x16x32_bf16(aH[mi], bF[ni], acc[mi][ni], 0, 0, 0);
        if constexpr (SPLITA)
          acc[mi][ni] = __builtin_amdgcn_mfma_f32_16x16x32_bf16(aL[mi], bF[ni], acc[mi][ni], 0, 0, 0);
      }
  };

  // prologue: stage tile 0, drain, barrier
  do_stage(0, 0);
  __syncthreads();                 // compiler emits vmcnt(0)+lgkmcnt(0) drain here
  int cur = 0;
  for (int kt = 1; kt < NKT; ++kt) {
    do_stage(cur ^ 1, kt);         // issue next-tile loads BEFORE compute
    do_compute(cur);
    __syncthreads();               // single drain+barrier per tile
    cur ^= 1;
  }
  do_compute(cur);                 // epilogue tile, no prefetch

  const int c = lane & 15, rg = lane >> 4;
  const int sbase = m0 + wm * 64, nbase = n0 + wn * 64;
  if constexpr (MODE == 0) {
#pragma unroll
    for (int mi = 0; mi < 4; ++mi)
#pragma unroll
      for (int ni = 0; ni < 4; ++ni) {
        int n = nbase + ni * 16 + c;
        float bv = bias[(size_t)e * NTOT + n];
#pragma unroll
        for (int r = 0; r < 4; ++r) {
          int slot = sbase + mi * 16 + rg * 4 + r;
          float val = acc[mi][ni][r] + bv;
          float other = __shfl_xor(val, 1);
          if (!(c & 1) && slot < cnt) {
            int tok = tok_s[slot - m0];
            float g = fminf(val, 7.0f);
            float u = fminf(fmaxf(other, -7.0f), 7.0f);
            float glu = g / (1.0f + expf(-1.702f * g));
            float mv = (u + 1.0f) * glu;
            float s = scores[tok * NE + e];
            midH[((size_t)e * T_TOK + slot) * DDIM + ((uint)n >> 1)] = f2bf(mv * s);
          }
        }
      }
  } else {
#pragma unroll
    for (int mi = 0; mi < 4; ++mi)
#pragma unroll
      for (int ni = 0; ni < 4; ++ni) {
        int n = nbase + ni * 16 + c;
        float dbv = bias[(size_t)e * NTOT + n];
#pragma unroll
        for (int r = 0; r < 4; ++r) {
          int slot = sbase + mi * 16 + rg * 4 + r;
          if (slot < cnt) {
            int tok = tok_s[slot - m0];
            float s = scores[tok * NE + e];
            atomicAdd(outp + (size_t)tok * HDIM + n, acc[mi][ni][r] + s * dbv);
          }
        }
      }
  }
}

extern "C" void kernel_launch(void* const* d_in, const int* in_sizes, int n_in,
                              void* d_out, int out_size, void* d_ws, size_t ws_size,
                              hipStream_t stream)
{
  const float* x      = (const float*)d_in[0];
  const float* nw     = (const float*)d_in[1];
  const float* rw     = (const float*)d_in[2];
  const float* rb     = (const float*)d_in[3];
  const int*   gus    = (const int*)d_in[4];
  const int*   gub    = (const int*)d_in[5];
  const float* gubias = (const float*)d_in[6];
  const int*   dns    = (const int*)d_in[7];
  const int*   dnb    = (const int*)d_in[8];
  const float* dnbias = (const float*)d_in[9];

  char* ws = (char*)d_ws;
  const size_t SZ_WGU = (size_t)NE * 4096 * 2048 * 2;   // 134 MB
  const size_t SZ_WDN = (size_t)NE * 2048 * 2048 * 2;   //  67 MB
  const size_t SZ_T   = (size_t)T_TOK * HDIM * 2;       //   4 MB (per plane)
  const size_t SZ_MID = (size_t)NE * T_TOK * DDIM * 2;  //  33.5 MB
  const size_t SZ_SC  = (size_t)T_TOK * NE * 4;
  const size_t SZ_IDX = (size_t)NE * T_TOK * 4;
  const size_t SZ_CNT = 128;

  const size_t need_act = 2 * SZ_T + SZ_MID + SZ_SC + SZ_IDX + SZ_CNT;
  const bool predeq = ws_size >= SZ_WGU + SZ_WDN + need_act;
  ushort* wgu = (ushort*)ws;
  ushort* wdn = (ushort*)(ws + SZ_WGU);
  char* base2 = predeq ? (ws + SZ_WGU + SZ_WDN) : ws;
  ushort* thi    = (ushort*)base2;
  ushort* tlo    = (ushort*)(base2 + SZ_T);
  ushort* midHp  = (ushort*)(base2 + 2 * SZ_T);
  float*  scores = (float*)(base2 + 2 * SZ_T + SZ_MID);
  int*    cnts   = (int*)(base2 + 2 * SZ_T + SZ_MID + SZ_SC);
  int*    tokidx = (int*)(base2 + 2 * SZ_T + SZ_MID + SZ_SC + SZ_CNT);
  float*  outp   = (float*)d_out;

  router_kernel<<<T_TOK, 256, 0, stream>>>(x, nw, rw, rb, thi, tlo, scores);
  hipMemcpyAsync(d_out, (void*)x, (size_t)T_TOK * HDIM * 4, hipMemcpyDeviceToDevice, stream);
  scan_kernel<<<NE, 256, 0, stream>>>(scores, cnts, tokidx);
  if (predeq) {
    dequant_kernel<<<(NE * 4096 * 64 + NE * 2048 * 64) / 256, 256, 0, stream>>>(
        gub, gus, dnb, dns, wgu, wdn);
    mx_gemm<0, true, true><<<dim3(32, 8, NE), 256, 0, stream>>>(
        thi, tlo, wgu, nullptr, nullptr, gubias, scores, cnts, tokidx, midHp, nullptr);
    mx_gemm<1, true, false><<<dim3(16, 8, NE), 256, 0, stream>>>(
        midHp, nullptr, wdn, nullptr, nullptr, dnbias, scores, cnts, tokidx, nullptr, outp);
  } else {
    mx_gemm<0, false, true><<<dim3(32, 8, NE), 256, 0, stream>>>(
        thi, tlo, nullptr, gub, gus, gubias, scores, cnts, tokidx, midHp, nullptr);
    mx_gemm<1, false, false><<<dim3(16, 8, NE), 256, 0, stream>>>(
        midHp, nullptr, nullptr, dnb, dns, dnbias, scores, cnts, tokidx, nullptr, outp);
  }
}

// Round 7
// 409.694 us; speedup vs baseline: 1.3952x; 1.0501x over previous
//
#include <hip/hip_runtime.h>
#include <hip/hip_bf16.h>
#include <stdint.h>

#define T_TOK 1024
#define HDIM 2048
#define DDIM 2048
#define NE 8

typedef unsigned int uint;
typedef unsigned short ushort;

typedef __bf16 bf16x8 __attribute__((ext_vector_type(8)));
typedef float f32x4 __attribute__((ext_vector_type(4)));

typedef __attribute__((address_space(1))) const void v_g;
typedef __attribute__((address_space(3))) void v_l;

__device__ __forceinline__ ushort f2bf(float f) {
  uint u = __float_as_uint(f);
  u += 0x7fffu + ((u >> 16) & 1u);
  return (ushort)(u >> 16);
}
__device__ __forceinline__ float bf2f(ushort b) {
  uint u = (uint)b << 16;
  return __uint_as_float(u);
}

// e2m1 nibble * 2^(sc-127) -> bf16 bits (exact; flush exp<=0 to signed zero)
__device__ __forceinline__ uint dq1(uint nib, int sc) {
  uint m = nib & 7u;
  int e = (int)(m >> 1);
  int be = sc + e - 1;
  uint mant = (e != 0) ? ((m & 1u) << 6) : 0u;
  uint r = ((m != 0u) && (be > 0)) ? (((uint)be << 7) | mant) : 0u;
  return r | ((nib & 8u) << 12);
}
__device__ __forceinline__ uint dq2(uint b, int sc) {
  return dq1(b & 15u, sc) | (dq1((b >> 4) & 15u, sc) << 16);
}

// ---------------- RMSNorm + router (f32 logits, top-4 softmax) ----------------
__global__ __launch_bounds__(256) void router_kernel(
    const float* __restrict__ x, const float* __restrict__ nw,
    const float* __restrict__ rw, const float* __restrict__ rb,
    ushort* __restrict__ thi, ushort* __restrict__ tlo, float* __restrict__ scores)
{
  const int t = blockIdx.x, tid = threadIdx.x;
  const float4* xr = (const float4*)(x + (size_t)t * HDIM);
  float4 v0 = xr[tid * 2], v1 = xr[tid * 2 + 1];
  float ss = v0.x*v0.x + v0.y*v0.y + v0.z*v0.z + v0.w*v0.w
           + v1.x*v1.x + v1.y*v1.y + v1.z*v1.z + v1.w*v1.w;
  __shared__ float red[256];
  red[tid] = ss;
  __syncthreads();
  for (int s = 128; s > 0; s >>= 1) {
    if (tid < s) red[tid] += red[tid + s];
    __syncthreads();
  }
  const float rstd = rsqrtf(red[0] * (1.0f / HDIM) + 1e-5f);
  float xv[8] = {v0.x, v0.y, v0.z, v0.w, v1.x, v1.y, v1.z, v1.w};
  float lp[NE];
#pragma unroll
  for (int e = 0; e < NE; ++e) lp[e] = 0.f;
  union { ushort us[8]; uint4 v; } pkh, pkl;
  const int h0 = tid * 8;
#pragma unroll
  for (int j = 0; j < 8; ++j) {
    int h = h0 + j;
    float tn = xv[j] * rstd * nw[h];
    ushort hb = f2bf(tn);
    pkh.us[j] = hb;
    pkl.us[j] = f2bf(tn - bf2f(hb));
#pragma unroll
    for (int e = 0; e < NE; ++e) lp[e] += tn * rw[h * NE + e];
  }
  *(uint4*)(thi + (size_t)t * HDIM + h0) = pkh.v;
  *(uint4*)(tlo + (size_t)t * HDIM + h0) = pkl.v;
#pragma unroll
  for (int e = 0; e < NE; ++e)
#pragma unroll
    for (int off = 32; off > 0; off >>= 1) lp[e] += __shfl_down(lp[e], off);
  __shared__ float wred[4][NE];
  if ((tid & 63) == 0) {
#pragma unroll
    for (int e = 0; e < NE; ++e) wred[tid >> 6][e] = lp[e];
  }
  __syncthreads();
  if (tid == 0) {
    float lg[NE];
#pragma unroll
    for (int e = 0; e < NE; ++e)
      lg[e] = wred[0][e] + wred[1][e] + wred[2][e] + wred[3][e] + rb[e];
    bool used[NE] = {false, false, false, false, false, false, false, false};
    float tv[4]; int ti[4];
    for (int s = 0; s < 4; ++s) {          // ties: lowest index first (strict >)
      float best = -3.4e38f; int bi = 0;
      for (int e = 0; e < NE; ++e)
        if (!used[e] && lg[e] > best) { best = lg[e]; bi = e; }
      used[bi] = true; tv[s] = best; ti[s] = bi;
    }
    float den = 0.f, ev[4];
    for (int s = 0; s < 4; ++s) { ev[s] = expf(tv[s] - tv[0]); den += ev[s]; }
    float so[NE] = {0, 0, 0, 0, 0, 0, 0, 0};
    for (int s = 0; s < 4; ++s) so[ti[s]] = ev[s] / den;
#pragma unroll
    for (int e = 0; e < NE; ++e) scores[t * NE + e] = so[e];
  }
}

// ------------- per-expert token compaction (deterministic prefix scan) --------
__global__ __launch_bounds__(256) void scan_kernel(
    const float* __restrict__ scores, int* __restrict__ cnts, int* __restrict__ idx)
{
  const int e = blockIdx.x, tid = threadIdx.x;
  int loc[4], c = 0;
#pragma unroll
  for (int j = 0; j < 4; ++j) {
    int t = tid * 4 + j;
    loc[j] = (scores[t * NE + e] != 0.f) ? 1 : 0;
    c += loc[j];
  }
  __shared__ int sc[256];
  sc[tid] = c;
  __syncthreads();
  for (int off = 1; off < 256; off <<= 1) {
    int v = (tid >= off) ? sc[tid - off] : 0;
    __syncthreads();
    sc[tid] += v;
    __syncthreads();
  }
  int base = sc[tid] - c;
#pragma unroll
  for (int j = 0; j < 4; ++j)
    if (loc[j]) idx[e * T_TOK + base++] = tid * 4 + j;
  if (tid == 255) cnts[e] = sc[255];
}

// ---------------- mxfp4 -> bf16 pre-dequant (memory-bound) ----------------
__global__ __launch_bounds__(256) void dequant_kernel(
    const int* __restrict__ gub, const int* __restrict__ gus,
    const int* __restrict__ dnb, const int* __restrict__ dns,
    ushort* __restrict__ wgu, ushort* __restrict__ wdn)
{
  const int NG = NE * 4096 * 64;
  const int ND = NE * 2048 * 64;
  int tidg = blockIdx.x * 256 + threadIdx.x;
  if (tidg >= NG + ND) return;
  const int* qb; const int* qs; ushort* dst; int bi;
  if (tidg < NG) { bi = tidg; qb = gub; qs = gus; dst = wgu; }
  else           { bi = tidg - NG; qb = dnb; qs = dns; dst = wdn; }
  int sc = qs[bi];
  const int4* bp = (const int4*)(qb + (size_t)bi * 16);
  int4 q0 = bp[0], q1 = bp[1], q2 = bp[2], q3 = bp[3];
  uint w[16];
  w[0]=dq2(q0.x,sc);  w[1]=dq2(q0.y,sc);  w[2]=dq2(q0.z,sc);  w[3]=dq2(q0.w,sc);
  w[4]=dq2(q1.x,sc);  w[5]=dq2(q1.y,sc);  w[6]=dq2(q1.z,sc);  w[7]=dq2(q1.w,sc);
  w[8]=dq2(q2.x,sc);  w[9]=dq2(q2.y,sc);  w[10]=dq2(q2.z,sc); w[11]=dq2(q2.w,sc);
  w[12]=dq2(q3.x,sc); w[13]=dq2(q3.y,sc); w[14]=dq2(q3.z,sc); w[15]=dq2(q3.w,sc);
  uint4* o = (uint4*)(dst + (size_t)bi * 32);
  o[0] = make_uint4(w[0], w[1], w[2], w[3]);
  o[1] = make_uint4(w[4], w[5], w[6], w[7]);
  o[2] = make_uint4(w[8], w[9], w[10], w[11]);
  o[3] = make_uint4(w[12], w[13], w[14], w[15]);
}

// -------- gate_up GEMM: 128x256 block, 4 waves, wave tile 64x128, BK=64 -------
// A = gathered t (hi+lo planes), B = wgu (pre-dequant bf16), 1-phase staging.
// Epilogue: bias + GLU + score-scale -> compacted mid (single bf16).
__global__ __launch_bounds__(256, 2) void gu_gemm(
    const ushort* __restrict__ AH,
    const ushort* __restrict__ AL,
    const ushort* __restrict__ Bw,
    const float* __restrict__ bias,
    const float* __restrict__ scores,
    const int* __restrict__ cnts,
    const int* __restrict__ tokidx,
    ushort* __restrict__ midH)
{
  constexpr int NTOT = 2 * DDIM;
  constexpr int K = HDIM;
  const int nt = blockIdx.x, mt = blockIdx.y, e = blockIdx.z;
  const int cnt = cnts[e];
  const int m0 = mt * 128, n0 = nt * 256;
  if (m0 >= cnt) return;

  __shared__ __align__(16) ushort AsH[128 * 64];   // 16 KB
  __shared__ __align__(16) ushort AsL[128 * 64];   // 16 KB
  __shared__ __align__(16) ushort Bs[256 * 64];    // 32 KB
  __shared__ int tok_s[128];

  const int tid = threadIdx.x;
  const int lane = tid & 63;
  const int wv = tid >> 6;
  const int wm = wv >> 1, wn = wv & 1;            // 2x2 wave grid
  const int fr = lane & 15, kg = lane >> 4;

  if (tid < 128) {
    int sl = m0 + tid;
    tok_s[tid] = (sl < cnt) ? tokidx[e * T_TOK + sl] : 0;
  }
  __syncthreads();

  int arow[4];
#pragma unroll
  for (int j = 0; j < 4; ++j) arow[j] = tok_s[(tid + 256 * j) >> 3];

  f32x4 acc[4][8];
#pragma unroll
  for (int i = 0; i < 4; ++i)
#pragma unroll
    for (int j = 0; j < 8; ++j) acc[i][j] = f32x4{0.f, 0.f, 0.f, 0.f};

  for (int kt = 0; kt < K / 64; ++kt) {
    // A hi/lo: 128 rows x 64 K, source pre-swizzled chunk' = chunk ^ (row&7)
#pragma unroll
    for (int j = 0; j < 4; ++j) {
      int cidx = tid + 256 * j;
      int row = cidx >> 3, ck = cidx & 7;
      int sck = ck ^ (row & 7);
      size_t go = (size_t)arow[j] * K + kt * 64 + sck * 8;
      __builtin_amdgcn_global_load_lds((v_g*)(AH + go), (v_l*)((char*)AsH + cidx * 16), 16, 0, 0);
      __builtin_amdgcn_global_load_lds((v_g*)(AL + go), (v_l*)((char*)AsL + cidx * 16), 16, 0, 0);
    }
    // B: 256 rows x 64 K
#pragma unroll
    for (int j = 0; j < 8; ++j) {
      int cidx = tid + 256 * j;
      int row = cidx >> 3, ck = cidx & 7;
      int sck = ck ^ (row & 7);
      const ushort* g = Bw + ((size_t)e * NTOT + n0 + row) * K + kt * 64 + sck * 8;
      __builtin_amdgcn_global_load_lds((v_g*)g, (v_l*)((char*)Bs + cidx * 16), 16, 0, 0);
    }
    __syncthreads();
#pragma unroll
    for (int kh = 0; kh < 2; ++kh) {
      bf16x8 aH[4], aL[4], bF[8];
#pragma unroll
      for (int mi = 0; mi < 4; ++mi) {
        int r = wm * 64 + mi * 16 + fr;
        int ck = (kh * 4 + kg) ^ (r & 7);
        aH[mi] = *(const bf16x8*)((const char*)AsH + r * 128 + ck * 16);
        aL[mi] = *(const bf16x8*)((const char*)AsL + r * 128 + ck * 16);
      }
#pragma unroll
      for (int ni = 0; ni < 8; ++ni) {
        int r = wn * 128 + ni * 16 + fr;
        int ck = (kh * 4 + kg) ^ (r & 7);
        bF[ni] = *(const bf16x8*)((const char*)Bs + r * 128 + ck * 16);
      }
#pragma unroll
      for (int mi = 0; mi < 4; ++mi)
#pragma unroll
        for (int ni = 0; ni < 8; ++ni) {
          acc[mi][ni] = __builtin_amdgcn_mfma_f32_16x16x32_bf16(aH[mi], bF[ni], acc[mi][ni], 0, 0, 0);
          acc[mi][ni] = __builtin_amdgcn_mfma_f32_16x16x32_bf16(aL[mi], bF[ni], acc[mi][ni], 0, 0, 0);
        }
    }
    __syncthreads();
  }

  const int c = lane & 15, rg = lane >> 4;
  const int sbase = m0 + wm * 64, nbase = n0 + wn * 128;
#pragma unroll
  for (int mi = 0; mi < 4; ++mi)
#pragma unroll
    for (int ni = 0; ni < 8; ++ni) {
      int n = nbase + ni * 16 + c;
      float bv = bias[(size_t)e * NTOT + n];
#pragma unroll
      for (int r = 0; r < 4; ++r) {
        int slot = sbase + mi * 16 + rg * 4 + r;
        float val = acc[mi][ni][r] + bv;
        float other = __shfl_xor(val, 1);
        if (!(c & 1) && slot < cnt) {
          int tok = tok_s[slot - m0];
          float g = fminf(val, 7.0f);
          float u = fminf(fmaxf(other, -7.0f), 7.0f);
          float glu = g / (1.0f + expf(-1.702f * g));
          float mv = (u + 1.0f) * glu;
          float s = scores[tok * NE + e];
          midH[((size_t)e * T_TOK + slot) * DDIM + ((uint)n >> 1)] = f2bf(mv * s);
        }
      }
    }
}

// -------- down GEMM: 128x128, BK=32, 2-phase double-buffered (R6 proven) ------
// A = compacted mid (single bf16); scatter atomicAdd(out[tok], acc + s*bias).
template<bool PREDEQ>
__global__ __launch_bounds__(256) void dn_gemm(
    const ushort* __restrict__ Abase,
    const ushort* __restrict__ Bw,
    const int* __restrict__ qblocks,
    const int* __restrict__ qscales,
    const float* __restrict__ bias,
    const float* __restrict__ scores,
    const int* __restrict__ cnts,
    const int* __restrict__ tokidx,
    float* __restrict__ outp)
{
  constexpr int NTOT = HDIM;
  constexpr int K    = DDIM;
  constexpr int NKT  = K / 32;
  const int nt = blockIdx.x, mt = blockIdx.y, e = blockIdx.z;
  const int cnt = cnts[e];
  const int m0 = mt * 128, n0 = nt * 128;
  if (m0 >= cnt) return;
  const ushort* A = Abase + (size_t)e * T_TOK * DDIM;

  __shared__ __align__(16) ushort As[2][128 * 32];
  __shared__ __align__(16) ushort Bs[2][128 * 32];
  __shared__ int tok_s[128];

  const int tid = threadIdx.x;
  const int lane = tid & 63;
  const int wv = tid >> 6;
  const int wm = wv >> 1, wn = wv & 1;
  const int fr = lane & 15, kg = lane >> 4;

  if (tid < 128) {
    int sl = m0 + tid;
    tok_s[tid] = (sl < cnt) ? tokidx[e * T_TOK + sl] : 0;
  }
  __syncthreads();

  f32x4 acc[4][4];
#pragma unroll
  for (int i = 0; i < 4; ++i)
#pragma unroll
    for (int j = 0; j < 4; ++j) acc[i][j] = f32x4{0.f, 0.f, 0.f, 0.f};

  auto do_stage = [&](int buf, int kt) {
#pragma unroll
    for (int j = 0; j < 2; ++j) {
      int cidx = tid + 256 * j;
      int row = cidx >> 2, ck = cidx & 3;
      int gck = ck ^ ((row >> 1) & 3);
      size_t go = (size_t)(m0 + row) * K + kt * 32 + gck * 8;
      __builtin_amdgcn_global_load_lds((v_g*)(A + go),
          (v_l*)((char*)&As[buf][0] + cidx * 16), 16, 0, 0);
    }
    if constexpr (PREDEQ) {
#pragma unroll
      for (int j = 0; j < 2; ++j) {
        int cidx = tid + 256 * j;
        int row = cidx >> 2, ck = cidx & 3;
        int gck = ck ^ ((row >> 1) & 3);
        const ushort* g = Bw + ((size_t)e * NTOT + n0 + row) * K + kt * 32 + gck * 8;
        __builtin_amdgcn_global_load_lds((v_g*)g,
            (v_l*)((char*)&Bs[buf][0] + cidx * 16), 16, 0, 0);
      }
    } else {
      const int brow = tid >> 1, half = tid & 1;
      size_t bi = ((size_t)e * NTOT + n0 + brow) * (K / 32) + kt;
      int sc = qscales[bi];
      const int4* bp = (const int4*)(qblocks + bi * 16) + half * 2;
      int4 q0 = bp[0], q1 = bp[1];
      uint w[8];
      w[0]=dq2(q0.x,sc); w[1]=dq2(q0.y,sc); w[2]=dq2(q0.z,sc); w[3]=dq2(q0.w,sc);
      w[4]=dq2(q1.x,sc); w[5]=dq2(q1.y,sc); w[6]=dq2(q1.z,sc); w[7]=dq2(q1.w,sc);
      int s = (brow >> 1) & 3;
#pragma unroll
      for (int q = 0; q < 2; ++q) {
        int gc = half * 2 + q;
        int ckk = gc ^ s;
        *(uint4*)((char*)&Bs[buf][0] + brow * 64 + ckk * 16) =
            make_uint4(w[4*q], w[4*q+1], w[4*q+2], w[4*q+3]);
      }
    }
  };

  auto do_compute = [&](int buf) {
    bf16x8 aF[4], bF[4];
#pragma unroll
    for (int mi = 0; mi < 4; ++mi) {
      int r = wm * 64 + mi * 16 + fr;
      int ck = kg ^ ((r >> 1) & 3);
      aF[mi] = *(const bf16x8*)(&As[buf][r * 32 + ck * 8]);
    }
#pragma unroll
    for (int ni = 0; ni < 4; ++ni) {
      int r = wn * 64 + ni * 16 + fr;
      int ck = kg ^ ((r >> 1) & 3);
      bF[ni] = *(const bf16x8*)(&Bs[buf][r * 32 + ck * 8]);
    }
#pragma unroll
    for (int mi = 0; mi < 4; ++mi)
#pragma unroll
      for (int ni = 0; ni < 4; ++ni)
        acc[mi][ni] = __builtin_amdgcn_mfma_f32_16x16x32_bf16(aF[mi], bF[ni], acc[mi][ni], 0, 0, 0);
  };

  do_stage(0, 0);
  __syncthreads();
  int cur = 0;
  for (int kt = 1; kt < NKT; ++kt) {
    do_stage(cur ^ 1, kt);
    do_compute(cur);
    __syncthreads();
    cur ^= 1;
  }
  do_compute(cur);

  const int c = lane & 15, rg = lane >> 4;
  const int sbase = m0 + wm * 64, nbase = n0 + wn * 64;
#pragma unroll
  for (int mi = 0; mi < 4; ++mi)
#pragma unroll
    for (int ni = 0; ni < 4; ++ni) {
      int n = nbase + ni * 16 + c;
      float dbv = bias[(size_t)e * NTOT + n];
#pragma unroll
      for (int r = 0; r < 4; ++r) {
        int slot = sbase + mi * 16 + rg * 4 + r;
        if (slot < cnt) {
          int tok = tok_s[slot - m0];
          float s = scores[tok * NE + e];
          atomicAdd(outp + (size_t)tok * HDIM + n, acc[mi][ni][r] + s * dbv);
        }
      }
    }
}

// ---- fallback gate_up (inline dequant, 128x128 BK=64 1-phase, R5 path) -------
__global__ __launch_bounds__(256) void gu_gemm_q(
    const ushort* __restrict__ AH,
    const ushort* __restrict__ AL,
    const int* __restrict__ qblocks,
    const int* __restrict__ qscales,
    const float* __restrict__ bias,
    const float* __restrict__ scores,
    const int* __restrict__ cnts,
    const int* __restrict__ tokidx,
    ushort* __restrict__ midH)
{
  constexpr int NTOT = 2 * DDIM;
  constexpr int K = HDIM;
  const int nt = blockIdx.x, mt = blockIdx.y, e = blockIdx.z;
  const int cnt = cnts[e];
  const int m0 = mt * 128, n0 = nt * 128;
  if (m0 >= cnt) return;

  __shared__ __align__(16) ushort AsH[128 * 64];
  __shared__ __align__(16) ushort AsL[128 * 64];
  __shared__ __align__(16) ushort Bs[128 * 64];
  __shared__ int tok_s[128];

  const int tid = threadIdx.x;
  const int lane = tid & 63;
  const int wv = tid >> 6;
  const int wm = wv >> 1, wn = wv & 1;
  const int fr = lane & 15, kg = lane >> 4;

  if (tid < 128) {
    int sl = m0 + tid;
    tok_s[tid] = (sl < cnt) ? tokidx[e * T_TOK + sl] : 0;
  }
  __syncthreads();
  int arow[4];
#pragma unroll
  for (int j = 0; j < 4; ++j) arow[j] = tok_s[(tid + 256 * j) >> 3];

  f32x4 acc[4][4];
#pragma unroll
  for (int i = 0; i < 4; ++i)
#pragma unroll
    for (int j = 0; j < 4; ++j) acc[i][j] = f32x4{0.f, 0.f, 0.f, 0.f};

  for (int kt = 0; kt < K / 64; ++kt) {
#pragma unroll
    for (int j = 0; j < 4; ++j) {
      int cidx = tid + 256 * j;
      int row = cidx >> 3, ck = cidx & 7;
      int sck = ck ^ (row & 7);
      size_t go = (size_t)arow[j] * K + kt * 64 + sck * 8;
      __builtin_amdgcn_global_load_lds((v_g*)(AH + go), (v_l*)((char*)AsH + cidx * 16), 16, 0, 0);
      __builtin_amdgcn_global_load_lds((v_g*)(AL + go), (v_l*)((char*)AsL + cidx * 16), 16, 0, 0);
    }
    {
      const int brow = tid >> 1, bblk = tid & 1;
      int kb = kt * 2 + bblk;
      size_t bi = ((size_t)e * NTOT + n0 + brow) * (K / 32) + kb;
      int sc = qscales[bi];
      const int4* bp = (const int4*)(qblocks + bi * 16);
      int4 q0 = bp[0], q1 = bp[1], q2 = bp[2], q3 = bp[3];
      uint w[16];
      w[0]=dq2(q0.x,sc);  w[1]=dq2(q0.y,sc);  w[2]=dq2(q0.z,sc);  w[3]=dq2(q0.w,sc);
      w[4]=dq2(q1.x,sc);  w[5]=dq2(q1.y,sc);  w[6]=dq2(q1.z,sc);  w[7]=dq2(q1.w,sc);
      w[8]=dq2(q2.x,sc);  w[9]=dq2(q2.y,sc);  w[10]=dq2(q2.z,sc); w[11]=dq2(q2.w,sc);
      w[12]=dq2(q3.x,sc); w[13]=dq2(q3.y,sc); w[14]=dq2(q3.z,sc); w[15]=dq2(q3.w,sc);
#pragma unroll
      for (int q = 0; q < 4; ++q) {
        int ck = bblk * 4 + q;
        int sk = ck ^ (brow & 7);
        *(uint4*)((char*)Bs + brow * 128 + sk * 16) =
            make_uint4(w[4*q], w[4*q+1], w[4*q+2], w[4*q+3]);
      }
    }
    __syncthreads();
#pragma unroll
    for (int kh = 0; kh < 2; ++kh) {
      bf16x8 aH[4], aL[4], bF[4];
#pragma unroll
      for (int mi = 0; mi < 4; ++mi) {
        int r = wm * 64 + mi * 16 + fr;
        int ck = (kh * 4 + kg) ^ (r & 7);
        aH[mi] = *(const bf16x8*)((const char*)AsH + r * 128 + ck * 16);
        aL[mi] = *(const bf16x8*)((const char*)AsL + r * 128 + ck * 16);
      }
#pragma unroll
      for (int ni = 0; ni < 4; ++ni) {
        int r = wn * 64 + ni * 16 + fr;
        int ck = (kh * 4 + kg) ^ (r & 7);
        bF[ni] = *(const bf16x8*)((const char*)Bs + r * 128 + ck * 16);
      }
#pragma unroll
      for (int mi = 0; mi < 4; ++mi)
#pragma unroll
        for (int ni = 0; ni < 4; ++ni) {
          acc[mi][ni] = __builtin_amdgcn_mfma_f32_16x16x32_bf16(aH[mi], bF[ni], acc[mi][ni], 0, 0, 0);
          acc[mi][ni] = __builtin_amdgcn_mfma_f32_16x16x32_bf16(aL[mi], bF[ni], acc[mi][ni], 0, 0, 0);
        }
    }
    __syncthreads();
  }

  const int c = lane & 15, rg = lane >> 4;
  const int sbase = m0 + wm * 64, nbase = n0 + wn * 64;
#pragma unroll
  for (int mi = 0; mi < 4; ++mi)
#pragma unroll
    for (int ni = 0; ni < 4; ++ni) {
      int n = nbase + ni * 16 + c;
      float bv = bias[(size_t)e * NTOT + n];
#pragma unroll
      for (int r = 0; r < 4; ++r) {
        int slot = sbase + mi * 16 + rg * 4 + r;
        float val = acc[mi][ni][r] + bv;
        float other = __shfl_xor(val, 1);
        if (!(c & 1) && slot < cnt) {
          int tok = tok_s[slot - m0];
          float g = fminf(val, 7.0f);
          float u = fminf(fmaxf(other, -7.0f), 7.0f);
          float glu = g / (1.0f + expf(-1.702f * g));
          float mv = (u + 1.0f) * glu;
          float s = scores[tok * NE + e];
          midH[((size_t)e * T_TOK + slot) * DDIM + ((uint)n >> 1)] = f2bf(mv * s);
        }
      }
    }
}

extern "C" void kernel_launch(void* const* d_in, const int* in_sizes, int n_in,
                              void* d_out, int out_size, void* d_ws, size_t ws_size,
                              hipStream_t stream)
{
  const float* x      = (const float*)d_in[0];
  const float* nw     = (const float*)d_in[1];
  const float* rw     = (const float*)d_in[2];
  const float* rb     = (const float*)d_in[3];
  const int*   gus    = (const int*)d_in[4];
  const int*   gub    = (const int*)d_in[5];
  const float* gubias = (const float*)d_in[6];
  const int*   dns    = (const int*)d_in[7];
  const int*   dnb    = (const int*)d_in[8];
  const float* dnbias = (const float*)d_in[9];

  char* ws = (char*)d_ws;
  const size_t SZ_WGU = (size_t)NE * 4096 * 2048 * 2;   // 134 MB
  const size_t SZ_WDN = (size_t)NE * 2048 * 2048 * 2;   //  67 MB
  const size_t SZ_T   = (size_t)T_TOK * HDIM * 2;       //   4 MB (per plane)
  const size_t SZ_MID = (size_t)NE * T_TOK * DDIM * 2;  //  33.5 MB
  const size_t SZ_SC  = (size_t)T_TOK * NE * 4;
  const size_t SZ_IDX = (size_t)NE * T_TOK * 4;
  const size_t SZ_CNT = 128;

  const size_t need_act = 2 * SZ_T + SZ_MID + SZ_SC + SZ_IDX + SZ_CNT;
  const bool predeq = ws_size >= SZ_WGU + SZ_WDN + need_act;
  ushort* wgu = (ushort*)ws;
  ushort* wdn = (ushort*)(ws + SZ_WGU);
  char* base2 = predeq ? (ws + SZ_WGU + SZ_WDN) : ws;
  ushort* thi    = (ushort*)base2;
  ushort* tlo    = (ushort*)(base2 + SZ_T);
  ushort* midHp  = (ushort*)(base2 + 2 * SZ_T);
  float*  scores = (float*)(base2 + 2 * SZ_T + SZ_MID);
  int*    cnts   = (int*)(base2 + 2 * SZ_T + SZ_MID + SZ_SC);
  int*    tokidx = (int*)(base2 + 2 * SZ_T + SZ_MID + SZ_SC + SZ_CNT);
  float*  outp   = (float*)d_out;

  router_kernel<<<T_TOK, 256, 0, stream>>>(x, nw, rw, rb, thi, tlo, scores);
  hipMemcpyAsync(d_out, (void*)x, (size_t)T_TOK * HDIM * 4, hipMemcpyDeviceToDevice, stream);
  scan_kernel<<<NE, 256, 0, stream>>>(scores, cnts, tokidx);
  if (predeq) {
    dequant_kernel<<<(NE * 4096 * 64 + NE * 2048 * 64) / 256, 256, 0, stream>>>(
        gub, gus, dnb, dns, wgu, wdn);
    gu_gemm<<<dim3(16, 8, NE), 256, 0, stream>>>(
        thi, tlo, wgu, gubias, scores, cnts, tokidx, midHp);
    dn_gemm<true><<<dim3(16, 8, NE), 256, 0, stream>>>(
        midHp, wdn, nullptr, nullptr, dnbias, scores, cnts, tokidx, outp);
  } else {
    gu_gemm_q<<<dim3(32, 8, NE), 256, 0, stream>>>(
        thi, tlo, gub, gus, gubias, scores, cnts, tokidx, midHp);
    dn_gemm<false><<<dim3(16, 8, NE), 256, 0, stream>>>(
        midHp, nullptr, dnb, dns, dnbias, scores, cnts, tokidx, outp);
  }
}